// Round 5
// baseline (828.663 us; speedup 1.0000x reference)
//
#include <hip/hip_runtime.h>
#include <cstdint>

#define TPB 256

// ---------------------------------------------------------------------------
// EdgeGCN: 3x GCNConv (N=100k, 32->64->64->64) + per-edge MLP (136->64->32->1)
// R5: Agg(H@W) == Agg(H)@W for every layer -> fuse each linear into the
//     aggregate as a wave-matvec epilogue (W^T staged in LDS, pad-68 rows).
//     fill_csr packs (u, nrm) into one int2 stream.
// ---------------------------------------------------------------------------

__device__ __forceinline__ void fma_row64(float zi, const float* __restrict__ wrow,
                                          float* acc) {
  const float4* w4 = (const float4*)wrow;
#pragma unroll
  for (int j4 = 0; j4 < 16; ++j4) {
    float4 w = w4[j4];
    acc[4 * j4 + 0] = fmaf(zi, w.x, acc[4 * j4 + 0]);
    acc[4 * j4 + 1] = fmaf(zi, w.y, acc[4 * j4 + 1]);
    acc[4 * j4 + 2] = fmaf(zi, w.z, acc[4 * j4 + 2]);
    acc[4 * j4 + 3] = fmaf(zi, w.w, acc[4 * j4 + 3]);
  }
}

// --- zero cnt/fill + detect int64-vs-int32 edge_index ----------------------
__global__ __launch_bounds__(TPB) void prep(int* __restrict__ cnt,
                                            int* __restrict__ fill, int n,
                                            const int* __restrict__ ei,
                                            int* __restrict__ flag) {
  int i = blockIdx.x * TPB + threadIdx.x;
  if (i < n) { cnt[i] = 0; fill[i] = 0; }
  if (blockIdx.x == 0 && threadIdx.x == 0) {
    int o = 0;
    for (int k = 0; k < 32; ++k) o |= ei[2 * k + 1];  // high words if int64
    *flag = (o == 0) ? 1 : 0;
  }
}

// --- normalize indices to int32 + count in-degree --------------------------
__global__ __launch_bounds__(TPB) void normalize_count(const int* __restrict__ ei,
                                                       const int* __restrict__ flag,
                                                       int* __restrict__ uu,
                                                       int* __restrict__ vv,
                                                       int* __restrict__ cnt, int E) {
  int e = blockIdx.x * TPB + threadIdx.x;
  if (e >= E) return;
  int u, v;
  if (*flag) {  // int64 little-endian: low word at 2*k
    u = ei[2 * (size_t)e];
    v = ei[2 * ((size_t)E + e)];
  } else {
    u = ei[e];
    v = ei[(size_t)E + e];
  }
  uu[e] = u;
  vv[e] = v;
  atomicAdd(&cnt[v], 1);
}

// exclusive scan of cnt -> row_ptr (1024 elems/block) + dinv = rsqrt(cnt+1)
__global__ __launch_bounds__(TPB) void scan1(const int* __restrict__ cnt,
                                             int* __restrict__ out,
                                             int* __restrict__ bsums,
                                             float* __restrict__ dinv, int n) {
  __shared__ int tmp[TPB];
  int tid = threadIdx.x;
  int base = blockIdx.x * 1024 + tid * 4;
  int v0 = 0, v1 = 0, v2 = 0, v3 = 0;
  if (base + 0 < n) v0 = cnt[base + 0];
  if (base + 1 < n) v1 = cnt[base + 1];
  if (base + 2 < n) v2 = cnt[base + 2];
  if (base + 3 < n) v3 = cnt[base + 3];
  if (base + 0 < n) dinv[base + 0] = rsqrtf((float)v0 + 1.0f);
  if (base + 1 < n) dinv[base + 1] = rsqrtf((float)v1 + 1.0f);
  if (base + 2 < n) dinv[base + 2] = rsqrtf((float)v2 + 1.0f);
  if (base + 3 < n) dinv[base + 3] = rsqrtf((float)v3 + 1.0f);
  int s = v0 + v1 + v2 + v3;
  tmp[tid] = s;
  __syncthreads();
  for (int off = 1; off < TPB; off <<= 1) {
    int x = (tid >= off) ? tmp[tid - off] : 0;
    __syncthreads();
    tmp[tid] += x;
    __syncthreads();
  }
  int excl = tmp[tid] - s;
  if (tid == TPB - 1) bsums[blockIdx.x] = tmp[TPB - 1];
  if (base + 0 < n) out[base + 0] = excl;
  if (base + 1 < n) out[base + 1] = excl + v0;
  if (base + 2 < n) out[base + 2] = excl + v0 + v1;
  if (base + 3 < n) out[base + 3] = excl + v0 + v1 + v2;
}

__global__ void scan2(int* __restrict__ bsums, int nb) {
  if (threadIdx.x == 0 && blockIdx.x == 0) {
    int run = 0;
    for (int i = 0; i < nb; ++i) { int t = bsums[i]; bsums[i] = run; run += t; }
  }
}

__global__ __launch_bounds__(TPB) void scan3(int* __restrict__ row_ptr,
                                             const int* __restrict__ bsums, int n,
                                             int total) {
  int i = blockIdx.x * TPB + threadIdx.x;
  if (i < n) row_ptr[i] += bsums[i >> 10];
  if (i == 0) row_ptr[n] = total;
}

// --- CSR fill: pack (u, nrm) as int2; v and original edge id separate ------
__global__ __launch_bounds__(TPB) void fill_csr(const int* __restrict__ uu,
                                                const int* __restrict__ vv,
                                                const int* __restrict__ row_ptr,
                                                int* __restrict__ fill,
                                                const float* __restrict__ dinv,
                                                int2* __restrict__ un,
                                                int* __restrict__ v_sorted,
                                                int* __restrict__ e_orig, int E) {
  int e = blockIdx.x * TPB + threadIdx.x;
  if (e >= E) return;
  int u = uu[e], v = vv[e];
  int slot = row_ptr[v] + atomicAdd(&fill[v], 1);
  un[slot] = make_int2(u, __float_as_int(dinv[u] * dinv[v]));
  v_sorted[slot] = v;
  e_orig[slot] = e;
}

// --- layer 0 fused: H = relu(Agg(x) @ W0 + b0), x is 32-wide ---------------
// wave per node; half-wave gather scheme; matvec epilogue over 32 features.
__global__ __launch_bounds__(TPB) void agg_lin32(const float* __restrict__ X,
                                                 const int2* __restrict__ un,
                                                 const int* __restrict__ row_ptr,
                                                 const float* __restrict__ dinv,
                                                 const float* __restrict__ W,
                                                 const float* __restrict__ bias,
                                                 float* __restrict__ H, int n) {
  __shared__ __align__(16) float WsT[64 * 36];  // WsT[j*36+f] = W[f*64+j]
  __shared__ float bs[64];
  int tid = threadIdx.x;
  for (int idx = tid; idx < 32 * 64; idx += TPB) {
    int f = idx >> 6, j = idx & 63;
    WsT[j * 36 + f] = W[idx];
  }
  if (tid < 64) bs[tid] = bias[tid];
  __syncthreads();

  int wid = (blockIdx.x * TPB + tid) >> 6;  // node
  int lane = tid & 63;
  if (wid >= n) return;
  int f = lane & 31;
  int half = lane >> 5;
  float dv = dinv[wid];
  float acc0 = (half == 0) ? X[(size_t)wid * 32 + f] * dv * dv : 0.f;  // self-loop
  float acc1 = 0.f;
  int rs = row_ptr[wid], re = row_ptr[wid + 1];
  for (int base = rs; base < re; base += 64) {
    int m = re - base;
    if (m > 64) m = 64;
    int2 p = (lane < m) ? un[base + lane] : make_int2(0, 0);
    float wj = __int_as_float(p.y);
    int k = 0;
    for (; k + 3 < m; k += 4) {
      int uA = __shfl(p.x, k + half), uB = __shfl(p.x, k + 2 + half);
      float wA = __shfl(wj, k + half), wB = __shfl(wj, k + 2 + half);
      acc0 = fmaf(X[(size_t)uA * 32 + f], wA, acc0);
      acc1 = fmaf(X[(size_t)uB * 32 + f], wB, acc1);
    }
    for (; k < m; k += 2) {
      if (k + half < m) {
        int uA = __shfl(p.x, k + half);
        float wA = __shfl(wj, k + half);
        acc0 = fmaf(X[(size_t)uA * 32 + f], wA, acc0);
      }
    }
  }
  float tot = acc0 + acc1;
  tot += __shfl_xor(tot, 32);  // both halves hold full sum for feature f

  // matvec: out[lane] = bs[lane] + sum_f tot_f * W[f][lane]
  const float4* wt4 = (const float4*)&WsT[lane * 36];
  float o0 = bs[lane], o1 = 0.f, o2 = 0.f, o3 = 0.f;
#pragma unroll
  for (int f4 = 0; f4 < 8; f4 += 4) {
    float4 wa = wt4[f4 + 0], wb = wt4[f4 + 1], wc = wt4[f4 + 2], wd = wt4[f4 + 3];
    o0 = fmaf(__shfl(tot, 4 * f4 + 0), wa.x, o0);
    o0 = fmaf(__shfl(tot, 4 * f4 + 1), wa.y, o0);
    o1 = fmaf(__shfl(tot, 4 * f4 + 2), wa.z, o1);
    o1 = fmaf(__shfl(tot, 4 * f4 + 3), wa.w, o1);
    o2 = fmaf(__shfl(tot, 4 * f4 + 4), wb.x, o2);
    o2 = fmaf(__shfl(tot, 4 * f4 + 5), wb.y, o2);
    o3 = fmaf(__shfl(tot, 4 * f4 + 6), wb.z, o3);
    o3 = fmaf(__shfl(tot, 4 * f4 + 7), wb.w, o3);
    o0 = fmaf(__shfl(tot, 4 * f4 + 8), wc.x, o0);
    o0 = fmaf(__shfl(tot, 4 * f4 + 9), wc.y, o0);
    o1 = fmaf(__shfl(tot, 4 * f4 + 10), wc.z, o1);
    o1 = fmaf(__shfl(tot, 4 * f4 + 11), wc.w, o1);
    o2 = fmaf(__shfl(tot, 4 * f4 + 12), wd.x, o2);
    o2 = fmaf(__shfl(tot, 4 * f4 + 13), wd.y, o2);
    o3 = fmaf(__shfl(tot, 4 * f4 + 14), wd.z, o3);
    o3 = fmaf(__shfl(tot, 4 * f4 + 15), wd.w, o3);
  }
  H[(size_t)wid * 64 + lane] = fmaxf((o0 + o1) + (o2 + o3), 0.f);
}

// --- layers 1/2 fused: Hout = relu(Agg(Hin) @ W + b), 64-wide --------------
__global__ __launch_bounds__(TPB) void agg_lin64(const float* __restrict__ Hin,
                                                 const int2* __restrict__ un,
                                                 const int* __restrict__ row_ptr,
                                                 const float* __restrict__ dinv,
                                                 const float* __restrict__ W,
                                                 const float* __restrict__ bias,
                                                 float* __restrict__ Hout, int n) {
  __shared__ __align__(16) float WsT[64 * 68];  // WsT[j*68+f] = W[f*64+j]
  __shared__ float bs[64];
  int tid = threadIdx.x;
  for (int idx = tid; idx < 64 * 64; idx += TPB) {
    int f = idx >> 6, j = idx & 63;
    WsT[j * 68 + f] = W[idx];
  }
  if (tid < 64) bs[tid] = bias[tid];
  __syncthreads();

  int wid = (blockIdx.x * TPB + tid) >> 6;  // node
  int lane = tid & 63;                      // feature
  if (wid >= n) return;
  float dv = dinv[wid];
  float acc0 = Hin[(size_t)wid * 64 + lane] * dv * dv;  // self-loop
  float acc1 = 0.f, acc2 = 0.f, acc3 = 0.f;
  int rs = row_ptr[wid], re = row_ptr[wid + 1];
  for (int base = rs; base < re; base += 64) {
    int m = re - base;
    if (m > 64) m = 64;
    int2 p = (lane < m) ? un[base + lane] : make_int2(0, 0);
    float wj = __int_as_float(p.y);
    int k = 0;
    for (; k + 3 < m; k += 4) {
      int u0 = __shfl(p.x, k), u1 = __shfl(p.x, k + 1);
      int u2 = __shfl(p.x, k + 2), u3 = __shfl(p.x, k + 3);
      float w0 = __shfl(wj, k), w1 = __shfl(wj, k + 1);
      float w2 = __shfl(wj, k + 2), w3 = __shfl(wj, k + 3);
      acc0 = fmaf(Hin[(size_t)u0 * 64 + lane], w0, acc0);
      acc1 = fmaf(Hin[(size_t)u1 * 64 + lane], w1, acc1);
      acc2 = fmaf(Hin[(size_t)u2 * 64 + lane], w2, acc2);
      acc3 = fmaf(Hin[(size_t)u3 * 64 + lane], w3, acc3);
    }
    for (; k < m; ++k) {
      int u0 = __shfl(p.x, k);
      float w0 = __shfl(wj, k);
      acc0 = fmaf(Hin[(size_t)u0 * 64 + lane], w0, acc0);
    }
  }
  float tot = (acc0 + acc1) + (acc2 + acc3);  // feature `lane` of Agg(Hin)[wid]

  // matvec: out[lane] = bs[lane] + sum_f tot_f * W[f][lane]
  const float4* wt4 = (const float4*)&WsT[lane * 68];
  float o0 = bs[lane], o1 = 0.f, o2 = 0.f, o3 = 0.f;
#pragma unroll
  for (int f4 = 0; f4 < 16; f4 += 4) {
    float4 wa = wt4[f4 + 0], wb = wt4[f4 + 1], wc = wt4[f4 + 2], wd = wt4[f4 + 3];
    o0 = fmaf(__shfl(tot, 4 * f4 + 0), wa.x, o0);
    o0 = fmaf(__shfl(tot, 4 * f4 + 1), wa.y, o0);
    o1 = fmaf(__shfl(tot, 4 * f4 + 2), wa.z, o1);
    o1 = fmaf(__shfl(tot, 4 * f4 + 3), wa.w, o1);
    o2 = fmaf(__shfl(tot, 4 * f4 + 4), wb.x, o2);
    o2 = fmaf(__shfl(tot, 4 * f4 + 5), wb.y, o2);
    o3 = fmaf(__shfl(tot, 4 * f4 + 6), wb.z, o3);
    o3 = fmaf(__shfl(tot, 4 * f4 + 7), wb.w, o3);
    o0 = fmaf(__shfl(tot, 4 * f4 + 8), wc.x, o0);
    o0 = fmaf(__shfl(tot, 4 * f4 + 9), wc.y, o0);
    o1 = fmaf(__shfl(tot, 4 * f4 + 10), wc.z, o1);
    o1 = fmaf(__shfl(tot, 4 * f4 + 11), wc.w, o1);
    o2 = fmaf(__shfl(tot, 4 * f4 + 12), wd.x, o2);
    o2 = fmaf(__shfl(tot, 4 * f4 + 13), wd.y, o2);
    o3 = fmaf(__shfl(tot, 4 * f4 + 14), wd.z, o3);
    o3 = fmaf(__shfl(tot, 4 * f4 + 15), wd.w, o3);
  }
  Hout[(size_t)wid * 64 + lane] = fmaxf((o0 + o1) + (o2 + o3), 0.f);
}

// --- fused apre/bpre: apre = A@W[0:64], bpre = A@W[64:128] -----------------
__global__ __launch_bounds__(TPB) void lin_ab(const float* __restrict__ A,
                                              const float* __restrict__ W,
                                              float* __restrict__ apre,
                                              float* __restrict__ bpre, int n) {
  __shared__ __align__(16) float Ws[128 * 64];  // 32 KB
  int tid = threadIdx.x;
  for (int i = tid; i < 128 * 64; i += TPB) Ws[i] = W[i];
  __syncthreads();
  int node = blockIdx.x * TPB + tid;
  if (node >= n) return;
  const float4* a4 = (const float4*)(A + (size_t)node * 64);
  float acc[64];
#pragma unroll
  for (int j = 0; j < 64; ++j) acc[j] = 0.f;
  for (int i4 = 0; i4 < 16; ++i4) {
    float4 z = a4[i4];
    fma_row64(z.x, &Ws[(4 * i4 + 0) * 64], acc);
    fma_row64(z.y, &Ws[(4 * i4 + 1) * 64], acc);
    fma_row64(z.z, &Ws[(4 * i4 + 2) * 64], acc);
    fma_row64(z.w, &Ws[(4 * i4 + 3) * 64], acc);
  }
  float4* o4 = (float4*)(apre + (size_t)node * 64);
#pragma unroll
  for (int j4 = 0; j4 < 16; ++j4)
    o4[j4] = make_float4(acc[4 * j4 + 0], acc[4 * j4 + 1], acc[4 * j4 + 2],
                         acc[4 * j4 + 3]);
#pragma unroll
  for (int j = 0; j < 64; ++j) acc[j] = 0.f;
  for (int i4 = 0; i4 < 16; ++i4) {
    float4 z = a4[i4];  // L1-hot reread
    fma_row64(z.x, &Ws[(64 + 4 * i4 + 0) * 64], acc);
    fma_row64(z.y, &Ws[(64 + 4 * i4 + 1) * 64], acc);
    fma_row64(z.z, &Ws[(64 + 4 * i4 + 2) * 64], acc);
    fma_row64(z.w, &Ws[(64 + 4 * i4 + 3) * 64], acc);
  }
  o4 = (float4*)(bpre + (size_t)node * 64);
#pragma unroll
  for (int j4 = 0; j4 < 16; ++j4)
    o4[j4] = make_float4(acc[4 * j4 + 0], acc[4 * j4 + 1], acc[4 * j4 + 2],
                         acc[4 * j4 + 3]);
}

// --- edge MLP, CSR order, weights via uniform (scalar) loads ---------------
__global__ __launch_bounds__(TPB) void edge_mlp(
    const float* __restrict__ apre, const float* __restrict__ bpre,
    const int2* __restrict__ un, const int* __restrict__ v_sorted,
    const int* __restrict__ e_orig, const float* __restrict__ EF,
    const float* __restrict__ W1e,  // Wm1 + 128*64
    const float* __restrict__ bm1, const float* __restrict__ Wm2,
    const float* __restrict__ bm2, const float* __restrict__ Wm3,
    const float* __restrict__ bm3, float* __restrict__ out, int E) {
  int t = blockIdx.x * TPB + threadIdx.x;
  if (t >= E) return;
  int u = un[t].x, v = v_sorted[t], e = e_orig[t];
  const float4* a4 = (const float4*)(apre + (size_t)u * 64);
  const float4* b4 = (const float4*)(bpre + (size_t)v * 64);  // wave-shared row
  const float4* ef4 = (const float4*)(EF + (size_t)e * 8);

  float4 z0 = ef4[0], z1 = ef4[1];
  float acc[64];
#pragma unroll
  for (int j = 0; j < 64; ++j) acc[j] = bm1[j];  // uniform -> s_load
  fma_row64(z0.x, W1e + 0 * 64, acc);
  fma_row64(z0.y, W1e + 1 * 64, acc);
  fma_row64(z0.z, W1e + 2 * 64, acc);
  fma_row64(z0.w, W1e + 3 * 64, acc);
  fma_row64(z1.x, W1e + 4 * 64, acc);
  fma_row64(z1.y, W1e + 5 * 64, acc);
  fma_row64(z1.z, W1e + 6 * 64, acc);
  fma_row64(z1.w, W1e + 7 * 64, acc);

#pragma unroll
  for (int i4 = 0; i4 < 16; ++i4) {
    float4 za = a4[i4];
    float4 zb = b4[i4];
    acc[4 * i4 + 0] += za.x + zb.x;
    acc[4 * i4 + 1] += za.y + zb.y;
    acc[4 * i4 + 2] += za.z + zb.z;
    acc[4 * i4 + 3] += za.w + zb.w;
  }

  // layer 2: 64 -> 32, relu on inputs; weights uniform -> s_load
  float z2[32];
#pragma unroll
  for (int j = 0; j < 32; ++j) z2[j] = bm2[j];
#pragma unroll
  for (int i = 0; i < 64; ++i) {
    float zi = fmaxf(acc[i], 0.f);
    const float4* w4 = (const float4*)(Wm2 + i * 32);
#pragma unroll
    for (int j4 = 0; j4 < 8; ++j4) {
      float4 w = w4[j4];
      z2[4 * j4 + 0] = fmaf(zi, w.x, z2[4 * j4 + 0]);
      z2[4 * j4 + 1] = fmaf(zi, w.y, z2[4 * j4 + 1]);
      z2[4 * j4 + 2] = fmaf(zi, w.z, z2[4 * j4 + 2]);
      z2[4 * j4 + 3] = fmaf(zi, w.w, z2[4 * j4 + 3]);
    }
  }
  // layer 3: 32 -> 1
  float o = bm3[0];
#pragma unroll
  for (int i = 0; i < 32; ++i) o = fmaf(fmaxf(z2[i], 0.f), Wm3[i], o);
  out[e] = o;
}

// ---------------------------------------------------------------------------
extern "C" void kernel_launch(void* const* d_in, const int* in_sizes, int n_in,
                              void* d_out, int out_size, void* d_ws, size_t ws_size,
                              hipStream_t stream) {
  const float* x   = (const float*)d_in[0];
  const int*   ei  = (const int*)d_in[1];
  const float* ef  = (const float*)d_in[2];
  const float* W0  = (const float*)d_in[3];
  const float* b0  = (const float*)d_in[4];
  const float* W1  = (const float*)d_in[5];
  const float* b1  = (const float*)d_in[6];
  const float* W2  = (const float*)d_in[7];
  const float* b2  = (const float*)d_in[8];
  const float* Wm1 = (const float*)d_in[9];
  const float* bm1 = (const float*)d_in[10];
  const float* Wm2 = (const float*)d_in[11];
  const float* bm2 = (const float*)d_in[12];
  const float* Wm3 = (const float*)d_in[13];
  const float* bm3 = (const float*)d_in[14];
  float* out = (float*)d_out;

  const int N = in_sizes[0] / 32;
  const int E = in_sizes[2] / 8;

  // workspace carve (256B aligned)
  char* p = (char*)d_ws;
  auto carve = [&](size_t bytes) {
    void* r = (void*)p;
    p += ((bytes + 255) / 256) * 256;
    return r;
  };
  int*   cnt      = (int*)carve((size_t)N * 4);
  int*   row_ptr  = (int*)carve((size_t)(N + 1) * 4);
  int*   fill     = (int*)carve((size_t)N * 4);
  float* dinv     = (float*)carve((size_t)N * 4);
  int*   bsums    = (int*)carve(4096);
  int*   flag     = (int*)carve(256);
  int2*  un       = (int2*)carve((size_t)E * 8);
  int*   v_sorted = (int*)carve((size_t)E * 4);
  int*   e_orig   = (int*)carve((size_t)E * 4);
  float* bufB     = (float*)carve((size_t)N * 64 * 4);  // h2 / apre
  float* bpre     = (float*)carve((size_t)N * 64 * 4);  // bpre
  float* bufA     = (float*)carve((size_t)N * 64 * 4);  // h1/h3; head = uu/vv
  if ((size_t)(p - (char*)d_ws) > ws_size) return;  // ws too small: bail loudly

  // uu/vv alias head of bufA (dead after fill_csr, before bufA written)
  int* uu = (int*)bufA;
  int* vv = uu + E;

  const int EB = (E + TPB - 1) / TPB;
  const int NB = (N + TPB - 1) / TPB;
  const int SB = (N + 1023) / 1024;
  const int AB = (N + 3) / 4;  // 4 waves/block, wave per node

  prep<<<NB, TPB, 0, stream>>>(cnt, fill, N, ei, flag);
  normalize_count<<<EB, TPB, 0, stream>>>(ei, flag, uu, vv, cnt, E);
  scan1<<<SB, TPB, 0, stream>>>(cnt, row_ptr, bsums, dinv, N);
  scan2<<<1, 64, 0, stream>>>(bsums, SB);
  scan3<<<NB, TPB, 0, stream>>>(row_ptr, bsums, N, E);
  fill_csr<<<EB, TPB, 0, stream>>>(uu, vv, row_ptr, fill, dinv, un, v_sorted,
                                   e_orig, E);

  // GCN layers, fully fused (Agg then transform):
  agg_lin32<<<AB, TPB, 0, stream>>>(x, un, row_ptr, dinv, W0, b0, bufA, N);      // h1
  agg_lin64<<<AB, TPB, 0, stream>>>(bufA, un, row_ptr, dinv, W1, b1, bufB, N);   // h2
  agg_lin64<<<AB, TPB, 0, stream>>>(bufB, un, row_ptr, dinv, W2, b2, bufA, N);   // h3

  // edge-MLP layer-1 factorization: apre = h3@Wm1[0:64], bpre = h3@Wm1[64:128]
  lin_ab<<<NB, TPB, 0, stream>>>(bufA, Wm1, bufB, bpre, N);

  // edge MLP in CSR order (no LDS; weights via scalar loads)
  edge_mlp<<<EB, TPB, 0, stream>>>(bufB, bpre, un, v_sorted, e_orig, ef,
                                   Wm1 + 128 * 64, bm1, Wm2, bm2, Wm3, bm3, out, E);
}

// Round 6
// 617.002 us; speedup vs baseline: 1.3430x; 1.3430x over previous
//
#include <hip/hip_runtime.h>
#include <hip/hip_fp16.h>
#include <cstdint>

#define TPB 256

// ---------------------------------------------------------------------------
// EdgeGCN: 3x GCNConv (N=100k, 32->64->64->64) + per-edge MLP (136->64->32->1)
// R6: revert R5 fusion (regressed: per-block weight staging + LDS bank
//     conflicts). R4 pipeline + fp16 storage for all randomly-gathered
//     tensors (x, lin outputs, apre/bpre): halves gather bytes; fp32 accum.
// ---------------------------------------------------------------------------

__device__ __forceinline__ void fma_row64(float zi, const float* __restrict__ wrow,
                                          float* acc) {
  const float4* w4 = (const float4*)wrow;
#pragma unroll
  for (int j4 = 0; j4 < 16; ++j4) {
    float4 w = w4[j4];
    acc[4 * j4 + 0] = fmaf(zi, w.x, acc[4 * j4 + 0]);
    acc[4 * j4 + 1] = fmaf(zi, w.y, acc[4 * j4 + 1]);
    acc[4 * j4 + 2] = fmaf(zi, w.z, acc[4 * j4 + 2]);
    acc[4 * j4 + 3] = fmaf(zi, w.w, acc[4 * j4 + 3]);
  }
}

// --- zero cnt/fill + detect idx width + convert x -> fp16 ------------------
__global__ __launch_bounds__(TPB) void prep(int* __restrict__ cnt,
                                            int* __restrict__ fill, int n,
                                            const int* __restrict__ ei,
                                            int* __restrict__ flag,
                                            const float* __restrict__ x,
                                            __half* __restrict__ xh) {
  int i = blockIdx.x * TPB + threadIdx.x;
  if (i < n) {
    cnt[i] = 0;
    fill[i] = 0;
    const float4* x4 = (const float4*)(x + (size_t)i * 32);
    __half2* o = (__half2*)(xh + (size_t)i * 32);
#pragma unroll
    for (int j = 0; j < 8; ++j) {
      float4 v = x4[j];
      o[2 * j + 0] = __floats2half2_rn(v.x, v.y);
      o[2 * j + 1] = __floats2half2_rn(v.z, v.w);
    }
  }
  if (blockIdx.x == 0 && threadIdx.x == 0) {
    int o = 0;
    for (int k = 0; k < 32; ++k) o |= ei[2 * k + 1];  // high words if int64
    *flag = (o == 0) ? 1 : 0;
  }
}

// --- normalize indices to int32 + count in-degree --------------------------
__global__ __launch_bounds__(TPB) void normalize_count(const int* __restrict__ ei,
                                                       const int* __restrict__ flag,
                                                       int* __restrict__ uu,
                                                       int* __restrict__ vv,
                                                       int* __restrict__ cnt, int E) {
  int e = blockIdx.x * TPB + threadIdx.x;
  if (e >= E) return;
  int u, v;
  if (*flag) {  // int64 little-endian: low word at 2*k
    u = ei[2 * (size_t)e];
    v = ei[2 * ((size_t)E + e)];
  } else {
    u = ei[e];
    v = ei[(size_t)E + e];
  }
  uu[e] = u;
  vv[e] = v;
  atomicAdd(&cnt[v], 1);
}

// exclusive scan of cnt -> row_ptr (1024 elems/block) + dinv = rsqrt(cnt+1)
__global__ __launch_bounds__(TPB) void scan1(const int* __restrict__ cnt,
                                             int* __restrict__ out,
                                             int* __restrict__ bsums,
                                             float* __restrict__ dinv, int n) {
  __shared__ int tmp[TPB];
  int tid = threadIdx.x;
  int base = blockIdx.x * 1024 + tid * 4;
  int v0 = 0, v1 = 0, v2 = 0, v3 = 0;
  if (base + 0 < n) v0 = cnt[base + 0];
  if (base + 1 < n) v1 = cnt[base + 1];
  if (base + 2 < n) v2 = cnt[base + 2];
  if (base + 3 < n) v3 = cnt[base + 3];
  if (base + 0 < n) dinv[base + 0] = rsqrtf((float)v0 + 1.0f);
  if (base + 1 < n) dinv[base + 1] = rsqrtf((float)v1 + 1.0f);
  if (base + 2 < n) dinv[base + 2] = rsqrtf((float)v2 + 1.0f);
  if (base + 3 < n) dinv[base + 3] = rsqrtf((float)v3 + 1.0f);
  int s = v0 + v1 + v2 + v3;
  tmp[tid] = s;
  __syncthreads();
  for (int off = 1; off < TPB; off <<= 1) {
    int x = (tid >= off) ? tmp[tid - off] : 0;
    __syncthreads();
    tmp[tid] += x;
    __syncthreads();
  }
  int excl = tmp[tid] - s;
  if (tid == TPB - 1) bsums[blockIdx.x] = tmp[TPB - 1];
  if (base + 0 < n) out[base + 0] = excl;
  if (base + 1 < n) out[base + 1] = excl + v0;
  if (base + 2 < n) out[base + 2] = excl + v0 + v1;
  if (base + 3 < n) out[base + 3] = excl + v0 + v1 + v2;
}

__global__ void scan2(int* __restrict__ bsums, int nb) {
  if (threadIdx.x == 0 && blockIdx.x == 0) {
    int run = 0;
    for (int i = 0; i < nb; ++i) { int t = bsums[i]; bsums[i] = run; run += t; }
  }
}

__global__ __launch_bounds__(TPB) void scan3(int* __restrict__ row_ptr,
                                             const int* __restrict__ bsums, int n,
                                             int total) {
  int i = blockIdx.x * TPB + threadIdx.x;
  if (i < n) row_ptr[i] += bsums[i >> 10];
  if (i == 0) row_ptr[n] = total;
}

// --- CSR fill: pack (u, nrm) as int2; v and original edge id separate ------
__global__ __launch_bounds__(TPB) void fill_csr(const int* __restrict__ uu,
                                                const int* __restrict__ vv,
                                                const int* __restrict__ row_ptr,
                                                int* __restrict__ fill,
                                                const float* __restrict__ dinv,
                                                int2* __restrict__ un,
                                                int* __restrict__ v_sorted,
                                                int* __restrict__ e_orig, int E) {
  int e = blockIdx.x * TPB + threadIdx.x;
  if (e >= E) return;
  int u = uu[e], v = vv[e];
  int slot = row_ptr[v] + atomicAdd(&fill[v], 1);
  un[slot] = make_int2(u, __float_as_int(dinv[u] * dinv[v]));
  v_sorted[slot] = v;
  e_orig[slot] = e;
}

// --- layer-0 aggregate over fp16 x (32-wide rows). Half-wave scheme --------
__global__ __launch_bounds__(TPB) void aggregate32h(const __half* __restrict__ X,
                                                    const int2* __restrict__ un,
                                                    const int* __restrict__ row_ptr,
                                                    const float* __restrict__ dinv,
                                                    float* __restrict__ xagg, int n) {
  int wid = (blockIdx.x * TPB + threadIdx.x) >> 6;  // node
  int lane = threadIdx.x & 63;
  int f = lane & 31;
  int half = lane >> 5;
  if (wid >= n) return;
  float dv = dinv[wid];
  float acc0 =
      (half == 0) ? __half2float(X[(size_t)wid * 32 + f]) * dv * dv : 0.f;
  float acc1 = 0.f;
  int rs = row_ptr[wid], re = row_ptr[wid + 1];
  for (int base = rs; base < re; base += 64) {
    int m = re - base;
    if (m > 64) m = 64;
    int2 p = (lane < m) ? un[base + lane] : make_int2(0, 0);
    float wj = __int_as_float(p.y);
    int k = 0;
    for (; k + 3 < m; k += 4) {
      int uA = __shfl(p.x, k + half), uB = __shfl(p.x, k + 2 + half);
      float wA = __shfl(wj, k + half), wB = __shfl(wj, k + 2 + half);
      acc0 = fmaf(__half2float(X[(size_t)uA * 32 + f]), wA, acc0);
      acc1 = fmaf(__half2float(X[(size_t)uB * 32 + f]), wB, acc1);
    }
    for (; k < m; k += 2) {
      if (k + half < m) {
        int uA = __shfl(p.x, k + half);
        float wA = __shfl(wj, k + half);
        acc0 = fmaf(__half2float(X[(size_t)uA * 32 + f]), wA, acc0);
      }
    }
  }
  float tot = acc0 + acc1;
  tot += __shfl_xor(tot, 32);
  if (half == 0) xagg[(size_t)wid * 32 + f] = tot;
}

// --- layer-0 linear with bias+relu: H1 = relu(xagg @ W0 + b0), fp32 out ----
__global__ __launch_bounds__(TPB) void lin32_br(const float* __restrict__ A,
                                                const float* __restrict__ W,
                                                const float* __restrict__ bias,
                                                float* __restrict__ B, int n) {
  __shared__ __align__(16) float Ws[32 * 64];
  __shared__ float bs[64];
  int tid = threadIdx.x;
  for (int i = tid; i < 32 * 64; i += TPB) Ws[i] = W[i];
  if (tid < 64) bs[tid] = bias[tid];
  __syncthreads();
  int node = blockIdx.x * TPB + tid;
  if (node >= n) return;
  const float4* a4 = (const float4*)(A + (size_t)node * 32);
  float acc[64];
#pragma unroll
  for (int j = 0; j < 64; ++j) acc[j] = bs[j];
  for (int i4 = 0; i4 < 8; ++i4) {
    float4 z = a4[i4];
    fma_row64(z.x, &Ws[(4 * i4 + 0) * 64], acc);
    fma_row64(z.y, &Ws[(4 * i4 + 1) * 64], acc);
    fma_row64(z.z, &Ws[(4 * i4 + 2) * 64], acc);
    fma_row64(z.w, &Ws[(4 * i4 + 3) * 64], acc);
  }
  float4* b4 = (float4*)(B + (size_t)node * 64);
#pragma unroll
  for (int j4 = 0; j4 < 16; ++j4)
    b4[j4] = make_float4(fmaxf(acc[4 * j4 + 0], 0.f), fmaxf(acc[4 * j4 + 1], 0.f),
                         fmaxf(acc[4 * j4 + 2], 0.f), fmaxf(acc[4 * j4 + 3], 0.f));
}

// --- node linear (64 -> 64), fp32 in, fp16 out -----------------------------
__global__ __launch_bounds__(TPB) void lin_node64h(const float* __restrict__ A,
                                                   const float* __restrict__ W,
                                                   __half* __restrict__ Bh, int n) {
  __shared__ __align__(16) float Ws[64 * 64];
  int tid = threadIdx.x;
  for (int i = tid; i < 64 * 64; i += TPB) Ws[i] = W[i];
  __syncthreads();
  int node = blockIdx.x * TPB + tid;
  if (node >= n) return;
  const float4* a4 = (const float4*)(A + (size_t)node * 64);
  float acc[64];
#pragma unroll
  for (int j = 0; j < 64; ++j) acc[j] = 0.f;
  for (int i4 = 0; i4 < 16; ++i4) {
    float4 z = a4[i4];
    fma_row64(z.x, &Ws[(4 * i4 + 0) * 64], acc);
    fma_row64(z.y, &Ws[(4 * i4 + 1) * 64], acc);
    fma_row64(z.z, &Ws[(4 * i4 + 2) * 64], acc);
    fma_row64(z.w, &Ws[(4 * i4 + 3) * 64], acc);
  }
  __half2* o2 = (__half2*)(Bh + (size_t)node * 64);
#pragma unroll
  for (int j2 = 0; j2 < 32; ++j2)
    o2[j2] = __floats2half2_rn(acc[2 * j2 + 0], acc[2 * j2 + 1]);
}

// --- aggregation (64-wide, fp16 rows): wave per node; shfl broadcast -------
__global__ __launch_bounds__(TPB) void aggregateh(const __half* __restrict__ Bh,
                                                  const int2* __restrict__ un,
                                                  const int* __restrict__ row_ptr,
                                                  const float* __restrict__ dinv,
                                                  const float* __restrict__ bias,
                                                  float* __restrict__ A, int n) {
  int wid = (blockIdx.x * TPB + threadIdx.x) >> 6;  // node
  int lane = threadIdx.x & 63;                      // feature
  if (wid >= n) return;
  float dv = dinv[wid];
  float acc0 = __half2float(Bh[(size_t)wid * 64 + lane]) * dv * dv;  // self-loop
  float acc1 = 0.f, acc2 = 0.f, acc3 = 0.f;
  int rs = row_ptr[wid], re = row_ptr[wid + 1];
  for (int base = rs; base < re; base += 64) {
    int m = re - base;
    if (m > 64) m = 64;
    int2 p = (lane < m) ? un[base + lane] : make_int2(0, 0);
    float wj = __int_as_float(p.y);
    int k = 0;
    for (; k + 3 < m; k += 4) {
      int u0 = __shfl(p.x, k), u1 = __shfl(p.x, k + 1);
      int u2 = __shfl(p.x, k + 2), u3 = __shfl(p.x, k + 3);
      float w0 = __shfl(wj, k), w1 = __shfl(wj, k + 1);
      float w2 = __shfl(wj, k + 2), w3 = __shfl(wj, k + 3);
      acc0 = fmaf(__half2float(Bh[(size_t)u0 * 64 + lane]), w0, acc0);
      acc1 = fmaf(__half2float(Bh[(size_t)u1 * 64 + lane]), w1, acc1);
      acc2 = fmaf(__half2float(Bh[(size_t)u2 * 64 + lane]), w2, acc2);
      acc3 = fmaf(__half2float(Bh[(size_t)u3 * 64 + lane]), w3, acc3);
    }
    for (; k < m; ++k) {
      int u0 = __shfl(p.x, k);
      float w0 = __shfl(wj, k);
      acc0 = fmaf(__half2float(Bh[(size_t)u0 * 64 + lane]), w0, acc0);
    }
  }
  A[(size_t)wid * 64 + lane] =
      fmaxf((acc0 + acc1) + (acc2 + acc3) + bias[lane], 0.f);
}

// --- fused apre/bpre: fp16 outputs -----------------------------------------
__global__ __launch_bounds__(TPB) void lin_ab(const float* __restrict__ A,
                                              const float* __restrict__ W,
                                              __half* __restrict__ apre,
                                              __half* __restrict__ bpre, int n) {
  __shared__ __align__(16) float Ws[128 * 64];  // 32 KB
  int tid = threadIdx.x;
  for (int i = tid; i < 128 * 64; i += TPB) Ws[i] = W[i];
  __syncthreads();
  int node = blockIdx.x * TPB + tid;
  if (node >= n) return;
  const float4* a4 = (const float4*)(A + (size_t)node * 64);
  float acc[64];
#pragma unroll
  for (int j = 0; j < 64; ++j) acc[j] = 0.f;
  for (int i4 = 0; i4 < 16; ++i4) {
    float4 z = a4[i4];
    fma_row64(z.x, &Ws[(4 * i4 + 0) * 64], acc);
    fma_row64(z.y, &Ws[(4 * i4 + 1) * 64], acc);
    fma_row64(z.z, &Ws[(4 * i4 + 2) * 64], acc);
    fma_row64(z.w, &Ws[(4 * i4 + 3) * 64], acc);
  }
  __half2* o2 = (__half2*)(apre + (size_t)node * 64);
#pragma unroll
  for (int j2 = 0; j2 < 32; ++j2)
    o2[j2] = __floats2half2_rn(acc[2 * j2 + 0], acc[2 * j2 + 1]);
#pragma unroll
  for (int j = 0; j < 64; ++j) acc[j] = 0.f;
  for (int i4 = 0; i4 < 16; ++i4) {
    float4 z = a4[i4];  // L1-hot reread
    fma_row64(z.x, &Ws[(64 + 4 * i4 + 0) * 64], acc);
    fma_row64(z.y, &Ws[(64 + 4 * i4 + 1) * 64], acc);
    fma_row64(z.z, &Ws[(64 + 4 * i4 + 2) * 64], acc);
    fma_row64(z.w, &Ws[(64 + 4 * i4 + 3) * 64], acc);
  }
  o2 = (__half2*)(bpre + (size_t)node * 64);
#pragma unroll
  for (int j2 = 0; j2 < 32; ++j2)
    o2[j2] = __floats2half2_rn(acc[2 * j2 + 0], acc[2 * j2 + 1]);
}

// --- edge MLP, CSR order, fp16 apre/bpre, weights via scalar loads ---------
__global__ __launch_bounds__(TPB) void edge_mlp(
    const __half* __restrict__ apre, const __half* __restrict__ bpre,
    const int2* __restrict__ un, const int* __restrict__ v_sorted,
    const int* __restrict__ e_orig, const float* __restrict__ EF,
    const float* __restrict__ W1e,  // Wm1 + 128*64
    const float* __restrict__ bm1, const float* __restrict__ Wm2,
    const float* __restrict__ bm2, const float* __restrict__ Wm3,
    const float* __restrict__ bm3, float* __restrict__ out, int E) {
  int t = blockIdx.x * TPB + threadIdx.x;
  if (t >= E) return;
  int u = un[t].x, v = v_sorted[t], e = e_orig[t];
  const __half2* a2 = (const __half2*)(apre + (size_t)u * 64);
  const __half2* b2 = (const __half2*)(bpre + (size_t)v * 64);  // wave-shared
  const float4* ef4 = (const float4*)(EF + (size_t)e * 8);

  float4 z0 = ef4[0], z1 = ef4[1];
  float acc[64];
#pragma unroll
  for (int j = 0; j < 64; ++j) acc[j] = bm1[j];  // uniform -> s_load
  fma_row64(z0.x, W1e + 0 * 64, acc);
  fma_row64(z0.y, W1e + 1 * 64, acc);
  fma_row64(z0.z, W1e + 2 * 64, acc);
  fma_row64(z0.w, W1e + 3 * 64, acc);
  fma_row64(z1.x, W1e + 4 * 64, acc);
  fma_row64(z1.y, W1e + 5 * 64, acc);
  fma_row64(z1.z, W1e + 6 * 64, acc);
  fma_row64(z1.w, W1e + 7 * 64, acc);

#pragma unroll
  for (int i2 = 0; i2 < 32; ++i2) {
    float2 fa = __half22float2(a2[i2]);
    float2 fb = __half22float2(b2[i2]);
    acc[2 * i2 + 0] += fa.x + fb.x;
    acc[2 * i2 + 1] += fa.y + fb.y;
  }

  // layer 2: 64 -> 32, relu on inputs; weights uniform -> s_load
  float z2[32];
#pragma unroll
  for (int j = 0; j < 32; ++j) z2[j] = bm2[j];
#pragma unroll
  for (int i = 0; i < 64; ++i) {
    float zi = fmaxf(acc[i], 0.f);
    const float4* w4 = (const float4*)(Wm2 + i * 32);
#pragma unroll
    for (int j4 = 0; j4 < 8; ++j4) {
      float4 w = w4[j4];
      z2[4 * j4 + 0] = fmaf(zi, w.x, z2[4 * j4 + 0]);
      z2[4 * j4 + 1] = fmaf(zi, w.y, z2[4 * j4 + 1]);
      z2[4 * j4 + 2] = fmaf(zi, w.z, z2[4 * j4 + 2]);
      z2[4 * j4 + 3] = fmaf(zi, w.w, z2[4 * j4 + 3]);
    }
  }
  // layer 3: 32 -> 1
  float o = bm3[0];
#pragma unroll
  for (int i = 0; i < 32; ++i) o = fmaf(fmaxf(z2[i], 0.f), Wm3[i], o);
  out[e] = o;
}

// ---------------------------------------------------------------------------
extern "C" void kernel_launch(void* const* d_in, const int* in_sizes, int n_in,
                              void* d_out, int out_size, void* d_ws, size_t ws_size,
                              hipStream_t stream) {
  const float* x   = (const float*)d_in[0];
  const int*   ei  = (const int*)d_in[1];
  const float* ef  = (const float*)d_in[2];
  const float* W0  = (const float*)d_in[3];
  const float* b0  = (const float*)d_in[4];
  const float* W1  = (const float*)d_in[5];
  const float* b1  = (const float*)d_in[6];
  const float* W2  = (const float*)d_in[7];
  const float* b2  = (const float*)d_in[8];
  const float* Wm1 = (const float*)d_in[9];
  const float* bm1 = (const float*)d_in[10];
  const float* Wm2 = (const float*)d_in[11];
  const float* bm2 = (const float*)d_in[12];
  const float* Wm3 = (const float*)d_in[13];
  const float* bm3 = (const float*)d_in[14];
  float* out = (float*)d_out;

  const int N = in_sizes[0] / 32;
  const int E = in_sizes[2] / 8;

  // workspace carve (256B aligned)
  char* p = (char*)d_ws;
  auto carve = [&](size_t bytes) {
    void* r = (void*)p;
    p += ((bytes + 255) / 256) * 256;
    return r;
  };
  int*    cnt      = (int*)carve((size_t)N * 4);
  int*    row_ptr  = (int*)carve((size_t)(N + 1) * 4);
  int*    fill     = (int*)carve((size_t)N * 4);
  float*  dinv     = (float*)carve((size_t)N * 4);
  int*    bsums    = (int*)carve(4096);
  int*    flag     = (int*)carve(256);
  int2*   un       = (int2*)carve((size_t)E * 8);
  int*    v_sorted = (int*)carve((size_t)E * 4);
  int*    e_orig   = (int*)carve((size_t)E * 4);
  float*  hA       = (float*)carve((size_t)N * 64 * 4);  // h1/h3; head = uu/vv
  float*  hB       = (float*)carve((size_t)N * 64 * 4);  // h2; head = xagg
  __half* linh     = (__half*)carve((size_t)N * 64 * 2); // fp16 lin outputs
  __half* apreh    = (__half*)carve((size_t)N * 64 * 2); // head doubles as xh
  __half* bpreh    = (__half*)carve((size_t)N * 64 * 2);
  if ((size_t)(p - (char*)d_ws) > ws_size) return;  // ws too small: bail loudly

  // aliases (lifetime-disjoint):
  int* uu = (int*)hA;                 // dead after fill_csr; hA written later
  int* vv = uu + E;
  float* xagg = hB;                   // dead after lin32_br; hB written later
  __half* xh = apreh;                 // dead after aggregate32h; apreh later

  const int EB = (E + TPB - 1) / TPB;
  const int NB = (N + TPB - 1) / TPB;
  const int SB = (N + 1023) / 1024;
  const int AB = (N + 3) / 4;  // 4 waves/block, wave per node

  prep<<<NB, TPB, 0, stream>>>(cnt, fill, N, ei, flag, x, xh);
  normalize_count<<<EB, TPB, 0, stream>>>(ei, flag, uu, vv, cnt, E);
  scan1<<<SB, TPB, 0, stream>>>(cnt, row_ptr, bsums, dinv, N);
  scan2<<<1, 64, 0, stream>>>(bsums, SB);
  scan3<<<NB, TPB, 0, stream>>>(row_ptr, bsums, N, E);
  fill_csr<<<EB, TPB, 0, stream>>>(uu, vv, row_ptr, fill, dinv, un, v_sorted,
                                   e_orig, E);

  // GCN layer 0: aggregate fp16 x, then lin+bias+relu -> hA (h1, fp32)
  aggregate32h<<<AB, TPB, 0, stream>>>(xh, un, row_ptr, dinv, xagg, N);
  lin32_br<<<NB, TPB, 0, stream>>>(xagg, W0, b0, hA, N);
  // layer 1: lin (fp16 out) then aggregate -> hB (h2)
  lin_node64h<<<NB, TPB, 0, stream>>>(hA, W1, linh, N);
  aggregateh<<<AB, TPB, 0, stream>>>(linh, un, row_ptr, dinv, b1, hB, N);
  // layer 2 -> hA (h3)
  lin_node64h<<<NB, TPB, 0, stream>>>(hB, W2, linh, N);
  aggregateh<<<AB, TPB, 0, stream>>>(linh, un, row_ptr, dinv, b2, hA, N);

  // edge-MLP layer-1 factorization: apre/bpre fp16
  lin_ab<<<NB, TPB, 0, stream>>>(hA, Wm1, apreh, bpreh, N);

  // edge MLP in CSR order
  edge_mlp<<<EB, TPB, 0, stream>>>(apreh, bpreh, un, v_sorted, e_orig, ef,
                                   Wm1 + 128 * 64, bm1, Wm2, bm2, Wm3, bm3, out, E);
}

// Round 7
// 530.027 us; speedup vs baseline: 1.5634x; 1.1641x over previous
//
#include <hip/hip_runtime.h>
#include <hip/hip_fp16.h>
#include <cstdint>

#define TPB 256

typedef _Float16 h2 __attribute__((ext_vector_type(2)));

__device__ __forceinline__ float fdot2(h2 a, h2 b, float c) {
  return __builtin_amdgcn_fdot2(a, b, c, false);
}

// ---------------------------------------------------------------------------
// EdgeGCN: 3x GCNConv (N=100k, 32->64->64->64) + per-edge MLP (136->64->32->1)
// R7: edge MLP via v_dot2_f32_f16 (2 FMA/inst, fp32 accum; weights pre-packed
//     to half2 pairs); aggregates use half2 lanes + 2/4 nodes per wave for
//     more gather streams in flight.
// ---------------------------------------------------------------------------

__device__ __forceinline__ void fma_row64(float zi, const float* __restrict__ wrow,
                                          float* acc) {
  const float4* w4 = (const float4*)wrow;
#pragma unroll
  for (int j4 = 0; j4 < 16; ++j4) {
    float4 w = w4[j4];
    acc[4 * j4 + 0] = fmaf(zi, w.x, acc[4 * j4 + 0]);
    acc[4 * j4 + 1] = fmaf(zi, w.y, acc[4 * j4 + 1]);
    acc[4 * j4 + 2] = fmaf(zi, w.z, acc[4 * j4 + 2]);
    acc[4 * j4 + 3] = fmaf(zi, w.w, acc[4 * j4 + 3]);
  }
}

// --- zero cnt/fill + detect idx width + convert x -> fp16 ------------------
__global__ __launch_bounds__(TPB) void prep(int* __restrict__ cnt,
                                            int* __restrict__ fill, int n,
                                            const int* __restrict__ ei,
                                            int* __restrict__ flag,
                                            const float* __restrict__ x,
                                            __half* __restrict__ xh) {
  int i = blockIdx.x * TPB + threadIdx.x;
  if (i < n) {
    cnt[i] = 0;
    fill[i] = 0;
    const float4* x4 = (const float4*)(x + (size_t)i * 32);
    __half2* o = (__half2*)(xh + (size_t)i * 32);
#pragma unroll
    for (int j = 0; j < 8; ++j) {
      float4 v = x4[j];
      o[2 * j + 0] = __floats2half2_rn(v.x, v.y);
      o[2 * j + 1] = __floats2half2_rn(v.z, v.w);
    }
  }
  if (blockIdx.x == 0 && threadIdx.x == 0) {
    int o = 0;
    for (int k = 0; k < 32; ++k) o |= ei[2 * k + 1];  // high words if int64
    *flag = (o == 0) ? 1 : 0;
  }
}

// --- pack edge-MLP weights into half2 k-pairs ------------------------------
// w1p[j*4+kk] = (W1e[2kk][j], W1e[2kk+1][j]);  w2p[j*32+kk] = (Wm2[2kk][j], ...)
__global__ void prep_w(const float* __restrict__ W1e, const float* __restrict__ Wm2,
                       h2* __restrict__ w1p, h2* __restrict__ w2p) {
  int idx = threadIdx.x;  // 256 threads, 1 block
  {
    int j = idx >> 2, kk = idx & 3;
    h2 t = {(_Float16)W1e[(2 * kk) * 64 + j], (_Float16)W1e[(2 * kk + 1) * 64 + j]};
    w1p[idx] = t;
  }
  for (int i = idx; i < 1024; i += 256) {
    int j = i >> 5, kk = i & 31;
    h2 t = {(_Float16)Wm2[(2 * kk) * 32 + j], (_Float16)Wm2[(2 * kk + 1) * 32 + j]};
    w2p[i] = t;
  }
}

// --- normalize indices to int32 + count in-degree --------------------------
__global__ __launch_bounds__(TPB) void normalize_count(const int* __restrict__ ei,
                                                       const int* __restrict__ flag,
                                                       int* __restrict__ uu,
                                                       int* __restrict__ vv,
                                                       int* __restrict__ cnt, int E) {
  int e = blockIdx.x * TPB + threadIdx.x;
  if (e >= E) return;
  int u, v;
  if (*flag) {  // int64 little-endian: low word at 2*k
    u = ei[2 * (size_t)e];
    v = ei[2 * ((size_t)E + e)];
  } else {
    u = ei[e];
    v = ei[(size_t)E + e];
  }
  uu[e] = u;
  vv[e] = v;
  atomicAdd(&cnt[v], 1);
}

// exclusive scan of cnt -> row_ptr (1024 elems/block) + dinv = rsqrt(cnt+1)
__global__ __launch_bounds__(TPB) void scan1(const int* __restrict__ cnt,
                                             int* __restrict__ out,
                                             int* __restrict__ bsums,
                                             float* __restrict__ dinv, int n) {
  __shared__ int tmp[TPB];
  int tid = threadIdx.x;
  int base = blockIdx.x * 1024 + tid * 4;
  int v0 = 0, v1 = 0, v2 = 0, v3 = 0;
  if (base + 0 < n) v0 = cnt[base + 0];
  if (base + 1 < n) v1 = cnt[base + 1];
  if (base + 2 < n) v2 = cnt[base + 2];
  if (base + 3 < n) v3 = cnt[base + 3];
  if (base + 0 < n) dinv[base + 0] = rsqrtf((float)v0 + 1.0f);
  if (base + 1 < n) dinv[base + 1] = rsqrtf((float)v1 + 1.0f);
  if (base + 2 < n) dinv[base + 2] = rsqrtf((float)v2 + 1.0f);
  if (base + 3 < n) dinv[base + 3] = rsqrtf((float)v3 + 1.0f);
  int s = v0 + v1 + v2 + v3;
  tmp[tid] = s;
  __syncthreads();
  for (int off = 1; off < TPB; off <<= 1) {
    int x = (tid >= off) ? tmp[tid - off] : 0;
    __syncthreads();
    tmp[tid] += x;
    __syncthreads();
  }
  int excl = tmp[tid] - s;
  if (tid == TPB - 1) bsums[blockIdx.x] = tmp[TPB - 1];
  if (base + 0 < n) out[base + 0] = excl;
  if (base + 1 < n) out[base + 1] = excl + v0;
  if (base + 2 < n) out[base + 2] = excl + v0 + v1;
  if (base + 3 < n) out[base + 3] = excl + v0 + v1 + v2;
}

__global__ void scan2(int* __restrict__ bsums, int nb) {
  if (threadIdx.x == 0 && blockIdx.x == 0) {
    int run = 0;
    for (int i = 0; i < nb; ++i) { int t = bsums[i]; bsums[i] = run; run += t; }
  }
}

__global__ __launch_bounds__(TPB) void scan3(int* __restrict__ row_ptr,
                                             const int* __restrict__ bsums, int n,
                                             int total) {
  int i = blockIdx.x * TPB + threadIdx.x;
  if (i < n) row_ptr[i] += bsums[i >> 10];
  if (i == 0) row_ptr[n] = total;
}

// --- CSR fill: pack (u, nrm) as int2; v and original edge id separate ------
__global__ __launch_bounds__(TPB) void fill_csr(const int* __restrict__ uu,
                                                const int* __restrict__ vv,
                                                const int* __restrict__ row_ptr,
                                                int* __restrict__ fill,
                                                const float* __restrict__ dinv,
                                                int2* __restrict__ un,
                                                int* __restrict__ v_sorted,
                                                int* __restrict__ e_orig, int E) {
  int e = blockIdx.x * TPB + threadIdx.x;
  if (e >= E) return;
  int u = uu[e], v = vv[e];
  int slot = row_ptr[v] + atomicAdd(&fill[v], 1);
  un[slot] = make_int2(u, __float_as_int(dinv[u] * dinv[v]));
  v_sorted[slot] = v;
  e_orig[slot] = e;
}

// --- layer-0 aggregate over fp16 x (32-wide rows): 4 nodes/wave ------------
// quarter q = lane>>4 owns node; 16 lanes x half2 = 32 features.
__global__ __launch_bounds__(TPB) void aggregate32h(const __half* __restrict__ X,
                                                    const int2* __restrict__ un,
                                                    const int* __restrict__ row_ptr,
                                                    const float* __restrict__ dinv,
                                                    float* __restrict__ xagg, int n) {
  int wave = (blockIdx.x * TPB + threadIdx.x) >> 6;
  int lane = threadIdx.x & 63;
  int q = lane >> 4, f2 = lane & 15;
  int node = wave * 4 + q;
  bool valid = node < n;
  int rs = 0, re = 0;
  float dv = 0.f;
  if (valid) { rs = row_ptr[node]; re = row_ptr[node + 1]; dv = dinv[node]; }
  const __half2* selfp = (const __half2*)(X + (size_t)(valid ? node : 0) * 32);
  float2 sf = __half22float2(selfp[f2]);
  float2 acc0 = make_float2(sf.x * dv * dv, sf.y * dv * dv);
  float2 acc1 = make_float2(0.f, 0.f);
  int sb = q << 4;
  for (int base = rs; base < re; base += 16) {
    int m = re - base;
    if (m > 16) m = 16;
    int2 p = (f2 < m) ? un[base + f2] : make_int2(0, 0);
    float wj = __int_as_float(p.y);
    int k = 0;
    for (; k + 1 < m; k += 2) {
      int u0 = __shfl(p.x, sb + k), u1 = __shfl(p.x, sb + k + 1);
      float w0 = __shfl(wj, sb + k), w1 = __shfl(wj, sb + k + 1);
      float2 v0 = __half22float2(((const __half2*)(X + (size_t)u0 * 32))[f2]);
      float2 v1 = __half22float2(((const __half2*)(X + (size_t)u1 * 32))[f2]);
      acc0.x = fmaf(v0.x, w0, acc0.x);
      acc0.y = fmaf(v0.y, w0, acc0.y);
      acc1.x = fmaf(v1.x, w1, acc1.x);
      acc1.y = fmaf(v1.y, w1, acc1.y);
    }
    if (k < m) {
      int u0 = __shfl(p.x, sb + k);
      float w0 = __shfl(wj, sb + k);
      float2 v0 = __half22float2(((const __half2*)(X + (size_t)u0 * 32))[f2]);
      acc0.x = fmaf(v0.x, w0, acc0.x);
      acc0.y = fmaf(v0.y, w0, acc0.y);
    }
  }
  if (valid) {
    float2 r = make_float2(acc0.x + acc1.x, acc0.y + acc1.y);
    ((float2*)(xagg + (size_t)node * 32))[f2] = r;
  }
}

// --- layer-0 linear with bias+relu: H1 = relu(xagg @ W0 + b0), fp32 out ----
__global__ __launch_bounds__(TPB) void lin32_br(const float* __restrict__ A,
                                                const float* __restrict__ W,
                                                const float* __restrict__ bias,
                                                float* __restrict__ B, int n) {
  __shared__ __align__(16) float Ws[32 * 64];
  __shared__ float bs[64];
  int tid = threadIdx.x;
  for (int i = tid; i < 32 * 64; i += TPB) Ws[i] = W[i];
  if (tid < 64) bs[tid] = bias[tid];
  __syncthreads();
  int node = blockIdx.x * TPB + tid;
  if (node >= n) return;
  const float4* a4 = (const float4*)(A + (size_t)node * 32);
  float acc[64];
#pragma unroll
  for (int j = 0; j < 64; ++j) acc[j] = bs[j];
  for (int i4 = 0; i4 < 8; ++i4) {
    float4 z = a4[i4];
    fma_row64(z.x, &Ws[(4 * i4 + 0) * 64], acc);
    fma_row64(z.y, &Ws[(4 * i4 + 1) * 64], acc);
    fma_row64(z.z, &Ws[(4 * i4 + 2) * 64], acc);
    fma_row64(z.w, &Ws[(4 * i4 + 3) * 64], acc);
  }
  float4* b4 = (float4*)(B + (size_t)node * 64);
#pragma unroll
  for (int j4 = 0; j4 < 16; ++j4)
    b4[j4] = make_float4(fmaxf(acc[4 * j4 + 0], 0.f), fmaxf(acc[4 * j4 + 1], 0.f),
                         fmaxf(acc[4 * j4 + 2], 0.f), fmaxf(acc[4 * j4 + 3], 0.f));
}

// --- node linear (64 -> 64), fp32 in, fp16 out -----------------------------
__global__ __launch_bounds__(TPB) void lin_node64h(const float* __restrict__ A,
                                                   const float* __restrict__ W,
                                                   __half* __restrict__ Bh, int n) {
  __shared__ __align__(16) float Ws[64 * 64];
  int tid = threadIdx.x;
  for (int i = tid; i < 64 * 64; i += TPB) Ws[i] = W[i];
  __syncthreads();
  int node = blockIdx.x * TPB + tid;
  if (node >= n) return;
  const float4* a4 = (const float4*)(A + (size_t)node * 64);
  float acc[64];
#pragma unroll
  for (int j = 0; j < 64; ++j) acc[j] = 0.f;
  for (int i4 = 0; i4 < 16; ++i4) {
    float4 z = a4[i4];
    fma_row64(z.x, &Ws[(4 * i4 + 0) * 64], acc);
    fma_row64(z.y, &Ws[(4 * i4 + 1) * 64], acc);
    fma_row64(z.z, &Ws[(4 * i4 + 2) * 64], acc);
    fma_row64(z.w, &Ws[(4 * i4 + 3) * 64], acc);
  }
  __half2* o2 = (__half2*)(Bh + (size_t)node * 64);
#pragma unroll
  for (int j2 = 0; j2 < 32; ++j2)
    o2[j2] = __floats2half2_rn(acc[2 * j2 + 0], acc[2 * j2 + 1]);
}

// --- aggregation (64-wide, fp16 rows): 2 nodes/wave, half2 lanes -----------
__global__ __launch_bounds__(TPB) void aggregateh(const __half* __restrict__ Bh,
                                                  const int2* __restrict__ un,
                                                  const int* __restrict__ row_ptr,
                                                  const float* __restrict__ dinv,
                                                  const float* __restrict__ bias,
                                                  float* __restrict__ A, int n) {
  int wave = (blockIdx.x * TPB + threadIdx.x) >> 6;
  int lane = threadIdx.x & 63;
  int half = lane >> 5, f2 = lane & 31;
  int node = wave * 2 + half;
  bool valid = node < n;
  int rs = 0, re = 0;
  float dv = 0.f;
  if (valid) { rs = row_ptr[node]; re = row_ptr[node + 1]; dv = dinv[node]; }
  const __half2* selfp = (const __half2*)(Bh + (size_t)(valid ? node : 0) * 64);
  float2 sf = __half22float2(selfp[f2]);
  float2 acc0 = make_float2(sf.x * dv * dv, sf.y * dv * dv);
  float2 acc1 = make_float2(0.f, 0.f);
  float2 acc2 = make_float2(0.f, 0.f);
  float2 acc3 = make_float2(0.f, 0.f);
  int sb = half << 5;
  for (int base = rs; base < re; base += 32) {
    int m = re - base;
    if (m > 32) m = 32;
    int2 p = (f2 < m) ? un[base + f2] : make_int2(0, 0);
    float wj = __int_as_float(p.y);
    int k = 0;
    for (; k + 3 < m; k += 4) {
      int u0 = __shfl(p.x, sb + k), u1 = __shfl(p.x, sb + k + 1);
      int u2 = __shfl(p.x, sb + k + 2), u3 = __shfl(p.x, sb + k + 3);
      float w0 = __shfl(wj, sb + k), w1 = __shfl(wj, sb + k + 1);
      float w2 = __shfl(wj, sb + k + 2), w3 = __shfl(wj, sb + k + 3);
      float2 v0 = __half22float2(((const __half2*)(Bh + (size_t)u0 * 64))[f2]);
      float2 v1 = __half22float2(((const __half2*)(Bh + (size_t)u1 * 64))[f2]);
      float2 v2 = __half22float2(((const __half2*)(Bh + (size_t)u2 * 64))[f2]);
      float2 v3 = __half22float2(((const __half2*)(Bh + (size_t)u3 * 64))[f2]);
      acc0.x = fmaf(v0.x, w0, acc0.x); acc0.y = fmaf(v0.y, w0, acc0.y);
      acc1.x = fmaf(v1.x, w1, acc1.x); acc1.y = fmaf(v1.y, w1, acc1.y);
      acc2.x = fmaf(v2.x, w2, acc2.x); acc2.y = fmaf(v2.y, w2, acc2.y);
      acc3.x = fmaf(v3.x, w3, acc3.x); acc3.y = fmaf(v3.y, w3, acc3.y);
    }
    for (; k < m; ++k) {
      int u0 = __shfl(p.x, sb + k);
      float w0 = __shfl(wj, sb + k);
      float2 v0 = __half22float2(((const __half2*)(Bh + (size_t)u0 * 64))[f2]);
      acc0.x = fmaf(v0.x, w0, acc0.x);
      acc0.y = fmaf(v0.y, w0, acc0.y);
    }
  }
  if (valid) {
    float2 bi = ((const float2*)bias)[f2];
    float2 r;
    r.x = fmaxf((acc0.x + acc1.x) + (acc2.x + acc3.x) + bi.x, 0.f);
    r.y = fmaxf((acc0.y + acc1.y) + (acc2.y + acc3.y) + bi.y, 0.f);
    ((float2*)(A + (size_t)node * 64))[f2] = r;
  }
}

// --- fused apre/bpre: fp16 outputs -----------------------------------------
__global__ __launch_bounds__(TPB) void lin_ab(const float* __restrict__ A,
                                              const float* __restrict__ W,
                                              __half* __restrict__ apre,
                                              __half* __restrict__ bpre, int n) {
  __shared__ __align__(16) float Ws[128 * 64];  // 32 KB
  int tid = threadIdx.x;
  for (int i = tid; i < 128 * 64; i += TPB) Ws[i] = W[i];
  __syncthreads();
  int node = blockIdx.x * TPB + tid;
  if (node >= n) return;
  const float4* a4 = (const float4*)(A + (size_t)node * 64);
  float acc[64];
#pragma unroll
  for (int j = 0; j < 64; ++j) acc[j] = 0.f;
  for (int i4 = 0; i4 < 16; ++i4) {
    float4 z = a4[i4];
    fma_row64(z.x, &Ws[(4 * i4 + 0) * 64], acc);
    fma_row64(z.y, &Ws[(4 * i4 + 1) * 64], acc);
    fma_row64(z.z, &Ws[(4 * i4 + 2) * 64], acc);
    fma_row64(z.w, &Ws[(4 * i4 + 3) * 64], acc);
  }
  __half2* o2 = (__half2*)(apre + (size_t)node * 64);
#pragma unroll
  for (int j2 = 0; j2 < 32; ++j2)
    o2[j2] = __floats2half2_rn(acc[2 * j2 + 0], acc[2 * j2 + 1]);
#pragma unroll
  for (int j = 0; j < 64; ++j) acc[j] = 0.f;
  for (int i4 = 0; i4 < 16; ++i4) {
    float4 z = a4[i4];  // L1-hot reread
    fma_row64(z.x, &Ws[(64 + 4 * i4 + 0) * 64], acc);
    fma_row64(z.y, &Ws[(64 + 4 * i4 + 1) * 64], acc);
    fma_row64(z.z, &Ws[(64 + 4 * i4 + 2) * 64], acc);
    fma_row64(z.w, &Ws[(64 + 4 * i4 + 3) * 64], acc);
  }
  o2 = (__half2*)(bpre + (size_t)node * 64);
#pragma unroll
  for (int j2 = 0; j2 < 32; ++j2)
    o2[j2] = __floats2half2_rn(acc[2 * j2 + 0], acc[2 * j2 + 1]);
}

// --- edge MLP, CSR order, fdot2 path ---------------------------------------
__global__ __launch_bounds__(TPB) void edge_mlp(
    const __half* __restrict__ apre, const __half* __restrict__ bpre,
    const int2* __restrict__ un, const int* __restrict__ v_sorted,
    const int* __restrict__ e_orig, const float* __restrict__ EF,
    const h2* __restrict__ w1p, const float* __restrict__ bm1,
    const h2* __restrict__ w2p, const float* __restrict__ bm2,
    const float* __restrict__ Wm3, const float* __restrict__ bm3,
    float* __restrict__ out, int E) {
  int t = blockIdx.x * TPB + threadIdx.x;
  if (t >= E) return;
  int u = un[t].x, v = v_sorted[t], e = e_orig[t];
  const h2* a2 = (const h2*)(apre + (size_t)u * 64);
  const h2* b2 = (const h2*)(bpre + (size_t)v * 64);  // wave-shared row
  const float4* ef4 = (const float4*)(EF + (size_t)e * 8);

  float4 z0 = ef4[0], z1 = ef4[1];
  h2 efh[4];
  efh[0] = h2{(_Float16)z0.x, (_Float16)z0.y};
  efh[1] = h2{(_Float16)z0.z, (_Float16)z0.w};
  efh[2] = h2{(_Float16)z1.x, (_Float16)z1.y};
  efh[3] = h2{(_Float16)z1.z, (_Float16)z1.w};
  const h2 selLo = h2{(_Float16)1.f, (_Float16)0.f};
  const h2 selHi = h2{(_Float16)0.f, (_Float16)1.f};

  // layer 1: acc[j] = bm1[j] + apre[u][j] + bpre[v][j] + ef . W1e[:,j]
  float acc[64];
#pragma unroll
  for (int j = 0; j < 64; ++j) {
    h2 sel = (j & 1) ? selHi : selLo;
    float a = fdot2(a2[j >> 1], sel, bm1[j]);
    a = fdot2(b2[j >> 1], sel, a);
    const h2* wp = w1p + j * 4;
    a = fdot2(efh[0], wp[0], a);
    a = fdot2(efh[1], wp[1], a);
    a = fdot2(efh[2], wp[2], a);
    a = fdot2(efh[3], wp[3], a);
    acc[j] = a;
  }

  // relu + pack to half2
  h2 zh[32];
#pragma unroll
  for (int i2 = 0; i2 < 32; ++i2)
    zh[i2] = h2{(_Float16)fmaxf(acc[2 * i2 + 0], 0.f),
                (_Float16)fmaxf(acc[2 * i2 + 1], 0.f)};

  // layer 2 (64->32) + layer 3 (32->1)
  float o = bm3[0];
#pragma unroll
  for (int j = 0; j < 32; ++j) {
    float z = bm2[j];
    const h2* wp = w2p + j * 32;
#pragma unroll
    for (int kk = 0; kk < 32; ++kk) z = fdot2(zh[kk], wp[kk], z);
    o = fmaf(fmaxf(z, 0.f), Wm3[j], o);
  }
  out[e] = o;
}

// ---------------------------------------------------------------------------
extern "C" void kernel_launch(void* const* d_in, const int* in_sizes, int n_in,
                              void* d_out, int out_size, void* d_ws, size_t ws_size,
                              hipStream_t stream) {
  const float* x   = (const float*)d_in[0];
  const int*   ei  = (const int*)d_in[1];
  const float* ef  = (const float*)d_in[2];
  const float* W0  = (const float*)d_in[3];
  const float* b0  = (const float*)d_in[4];
  const float* W1  = (const float*)d_in[5];
  const float* b1  = (const float*)d_in[6];
  const float* W2  = (const float*)d_in[7];
  const float* b2  = (const float*)d_in[8];
  const float* Wm1 = (const float*)d_in[9];
  const float* bm1 = (const float*)d_in[10];
  const float* Wm2 = (const float*)d_in[11];
  const float* bm2 = (const float*)d_in[12];
  const float* Wm3 = (const float*)d_in[13];
  const float* bm3 = (const float*)d_in[14];
  float* out = (float*)d_out;

  const int N = in_sizes[0] / 32;
  const int E = in_sizes[2] / 8;

  // workspace carve (256B aligned)
  char* p = (char*)d_ws;
  auto carve = [&](size_t bytes) {
    void* r = (void*)p;
    p += ((bytes + 255) / 256) * 256;
    return r;
  };
  int*    cnt      = (int*)carve((size_t)N * 4);
  int*    row_ptr  = (int*)carve((size_t)(N + 1) * 4);
  int*    fill     = (int*)carve((size_t)N * 4);
  float*  dinv     = (float*)carve((size_t)N * 4);
  int*    bsums    = (int*)carve(4096);
  int*    flag     = (int*)carve(256);
  h2*     w1p      = (h2*)carve(256 * 4);
  h2*     w2p      = (h2*)carve(1024 * 4);
  int2*   un       = (int2*)carve((size_t)E * 8);
  int*    v_sorted = (int*)carve((size_t)E * 4);
  int*    e_orig   = (int*)carve((size_t)E * 4);
  float*  hA       = (float*)carve((size_t)N * 64 * 4);  // h1/h3; head = uu/vv
  float*  hB       = (float*)carve((size_t)N * 64 * 4);  // h2; head = xagg
  __half* linh     = (__half*)carve((size_t)N * 64 * 2); // fp16 lin outputs
  __half* apreh    = (__half*)carve((size_t)N * 64 * 2); // head doubles as xh
  __half* bpreh    = (__half*)carve((size_t)N * 64 * 2);
  if ((size_t)(p - (char*)d_ws) > ws_size) return;  // ws too small: bail loudly

  // aliases (lifetime-disjoint):
  int* uu = (int*)hA;                 // dead after fill_csr; hA written later
  int* vv = uu + E;
  float* xagg = hB;                   // dead after lin32_br; hB written later
  __half* xh = apreh;                 // dead after aggregate32h; apreh later

  const int EB = (E + TPB - 1) / TPB;
  const int NB = (N + TPB - 1) / TPB;
  const int SB = (N + 1023) / 1024;
  const int AB2 = (((N + 1) / 2) + 3) / 4;  // 2 nodes/wave, 4 waves/block
  const int AB4 = (((N + 3) / 4) + 3) / 4;  // 4 nodes/wave, 4 waves/block

  prep<<<NB, TPB, 0, stream>>>(cnt, fill, N, ei, flag, x, xh);
  prep_w<<<1, TPB, 0, stream>>>(Wm1 + 128 * 64, Wm2, w1p, w2p);
  normalize_count<<<EB, TPB, 0, stream>>>(ei, flag, uu, vv, cnt, E);
  scan1<<<SB, TPB, 0, stream>>>(cnt, row_ptr, bsums, dinv, N);
  scan2<<<1, 64, 0, stream>>>(bsums, SB);
  scan3<<<NB, TPB, 0, stream>>>(row_ptr, bsums, N, E);
  fill_csr<<<EB, TPB, 0, stream>>>(uu, vv, row_ptr, fill, dinv, un, v_sorted,
                                   e_orig, E);

  // GCN layer 0: aggregate fp16 x (4 nodes/wave), then lin+bias+relu -> hA
  aggregate32h<<<AB4, TPB, 0, stream>>>(xh, un, row_ptr, dinv, xagg, N);
  lin32_br<<<NB, TPB, 0, stream>>>(xagg, W0, b0, hA, N);
  // layer 1: lin (fp16 out) then aggregate (2 nodes/wave) -> hB
  lin_node64h<<<NB, TPB, 0, stream>>>(hA, W1, linh, N);
  aggregateh<<<AB2, TPB, 0, stream>>>(linh, un, row_ptr, dinv, b1, hB, N);
  // layer 2 -> hA
  lin_node64h<<<NB, TPB, 0, stream>>>(hB, W2, linh, N);
  aggregateh<<<AB2, TPB, 0, stream>>>(linh, un, row_ptr, dinv, b2, hA, N);

  // edge-MLP layer-1 factorization: apre/bpre fp16
  lin_ab<<<NB, TPB, 0, stream>>>(hA, Wm1, apreh, bpreh, N);

  // edge MLP in CSR order (fdot2 path)
  edge_mlp<<<EB, TPB, 0, stream>>>(apreh, bpreh, un, v_sorted, e_orig, ef, w1p,
                                   bm1, w2p, bm2, Wm3, bm3, out, E);
}

// Round 8
// 523.509 us; speedup vs baseline: 1.5829x; 1.0125x over previous
//
#include <hip/hip_runtime.h>
#include <hip/hip_fp16.h>
#include <cstdint>

#define TPB 256

typedef _Float16 h2 __attribute__((ext_vector_type(2)));

__device__ __forceinline__ float fdot2(h2 a, h2 b, float c) {
  return __builtin_amdgcn_fdot2(a, b, c, false);
}

// per-CSR-slot packed edge metadata (32 B): endpoints, orig id, fp16 ef row
struct alignas(32) EMeta { int u, v, e, pad; h2 ef[4]; };

// ---------------------------------------------------------------------------
// EdgeGCN: 3x GCNConv (N=100k, 32->64->64->64) + per-edge MLP (136->64->32->1)
// R8: EMeta packing (ef delivered to edge_mlp as one coalesced 32 B stream,
//     no random ef gather); direct edge_index decode (normalize_count gone);
//     u_sorted-only neighbor stream with dv factored out of the sum.
// ---------------------------------------------------------------------------

__device__ __forceinline__ void fma_row64(float zi, const float* __restrict__ wrow,
                                          float* acc) {
  const float4* w4 = (const float4*)wrow;
#pragma unroll
  for (int j4 = 0; j4 < 16; ++j4) {
    float4 w = w4[j4];
    acc[4 * j4 + 0] = fmaf(zi, w.x, acc[4 * j4 + 0]);
    acc[4 * j4 + 1] = fmaf(zi, w.y, acc[4 * j4 + 1]);
    acc[4 * j4 + 2] = fmaf(zi, w.z, acc[4 * j4 + 2]);
    acc[4 * j4 + 3] = fmaf(zi, w.w, acc[4 * j4 + 3]);
  }
}

// --- zero cnt/fill + detect idx width + convert x -> fp16 ------------------
__global__ __launch_bounds__(TPB) void prep(int* __restrict__ cnt,
                                            int* __restrict__ fill, int n,
                                            const int* __restrict__ ei,
                                            int* __restrict__ flag,
                                            const float* __restrict__ x,
                                            __half* __restrict__ xh) {
  int i = blockIdx.x * TPB + threadIdx.x;
  if (i < n) {
    cnt[i] = 0;
    fill[i] = 0;
    const float4* x4 = (const float4*)(x + (size_t)i * 32);
    __half2* o = (__half2*)(xh + (size_t)i * 32);
#pragma unroll
    for (int j = 0; j < 8; ++j) {
      float4 v = x4[j];
      o[2 * j + 0] = __floats2half2_rn(v.x, v.y);
      o[2 * j + 1] = __floats2half2_rn(v.z, v.w);
    }
  }
  if (blockIdx.x == 0 && threadIdx.x == 0) {
    int o = 0;
    for (int k = 0; k < 32; ++k) o |= ei[2 * k + 1];  // high words if int64
    *flag = (o == 0) ? 1 : 0;
  }
}

// --- count in-degree, decoding edge_index directly -------------------------
__global__ __launch_bounds__(TPB) void count_deg(const int* __restrict__ ei,
                                                 const int* __restrict__ flag,
                                                 int* __restrict__ cnt, int E) {
  int e = blockIdx.x * TPB + threadIdx.x;
  if (e >= E) return;
  int v = (*flag) ? ei[2 * ((size_t)E + e)] : ei[(size_t)E + e];
  atomicAdd(&cnt[v], 1);
}

// exclusive scan of cnt -> row_ptr (1024 elems/block) + dinv = rsqrt(cnt+1)
__global__ __launch_bounds__(TPB) void scan1(const int* __restrict__ cnt,
                                             int* __restrict__ out,
                                             int* __restrict__ bsums,
                                             float* __restrict__ dinv, int n) {
  __shared__ int tmp[TPB];
  int tid = threadIdx.x;
  int base = blockIdx.x * 1024 + tid * 4;
  int v0 = 0, v1 = 0, v2 = 0, v3 = 0;
  if (base + 0 < n) v0 = cnt[base + 0];
  if (base + 1 < n) v1 = cnt[base + 1];
  if (base + 2 < n) v2 = cnt[base + 2];
  if (base + 3 < n) v3 = cnt[base + 3];
  if (base + 0 < n) dinv[base + 0] = rsqrtf((float)v0 + 1.0f);
  if (base + 1 < n) dinv[base + 1] = rsqrtf((float)v1 + 1.0f);
  if (base + 2 < n) dinv[base + 2] = rsqrtf((float)v2 + 1.0f);
  if (base + 3 < n) dinv[base + 3] = rsqrtf((float)v3 + 1.0f);
  int s = v0 + v1 + v2 + v3;
  tmp[tid] = s;
  __syncthreads();
  for (int off = 1; off < TPB; off <<= 1) {
    int x = (tid >= off) ? tmp[tid - off] : 0;
    __syncthreads();
    tmp[tid] += x;
    __syncthreads();
  }
  int excl = tmp[tid] - s;
  if (tid == TPB - 1) bsums[blockIdx.x] = tmp[TPB - 1];
  if (base + 0 < n) out[base + 0] = excl;
  if (base + 1 < n) out[base + 1] = excl + v0;
  if (base + 2 < n) out[base + 2] = excl + v0 + v1;
  if (base + 3 < n) out[base + 3] = excl + v0 + v1 + v2;
}

// --- block-sum scan (thread 0) + edge-MLP weight packing (all threads) -----
__global__ void scan2w(int* __restrict__ bsums, int nb,
                       const float* __restrict__ W1e, const float* __restrict__ Wm2,
                       h2* __restrict__ w1p, h2* __restrict__ w2p) {
  int idx = threadIdx.x;  // 256 threads, 1 block
  if (idx == 0) {
    int run = 0;
    for (int i = 0; i < nb; ++i) { int t = bsums[i]; bsums[i] = run; run += t; }
  }
  {
    int j = idx >> 2, kk = idx & 3;
    w1p[idx] =
        h2{(_Float16)W1e[(2 * kk) * 64 + j], (_Float16)W1e[(2 * kk + 1) * 64 + j]};
  }
  for (int i = idx; i < 1024; i += 256) {
    int j = i >> 5, kk = i & 31;
    w2p[i] =
        h2{(_Float16)Wm2[(2 * kk) * 32 + j], (_Float16)Wm2[(2 * kk + 1) * 32 + j]};
  }
}

__global__ __launch_bounds__(TPB) void scan3(int* __restrict__ row_ptr,
                                             const int* __restrict__ bsums, int n,
                                             int total) {
  int i = blockIdx.x * TPB + threadIdx.x;
  if (i < n) row_ptr[i] += bsums[i >> 10];
  if (i == 0) row_ptr[n] = total;
}

// --- CSR fill: u_sorted always; EMeta (META) or v_sorted/e_orig (!META) ----
template <bool META>
__global__ __launch_bounds__(TPB) void fill_csr(const int* __restrict__ ei,
                                                const int* __restrict__ flag,
                                                const int* __restrict__ row_ptr,
                                                int* __restrict__ fill,
                                                const float* __restrict__ EF,
                                                int* __restrict__ u_sorted,
                                                EMeta* __restrict__ emeta,
                                                int* __restrict__ v_sorted,
                                                int* __restrict__ e_orig, int E) {
  int e = blockIdx.x * TPB + threadIdx.x;
  if (e >= E) return;
  int u, v;
  if (*flag) {  // int64 little-endian: low word at 2*k
    u = ei[2 * (size_t)e];
    v = ei[2 * ((size_t)E + e)];
  } else {
    u = ei[e];
    v = ei[(size_t)E + e];
  }
  int slot = row_ptr[v] + atomicAdd(&fill[v], 1);
  u_sorted[slot] = u;
  if constexpr (META) {
    const float4* ef4 = (const float4*)(EF + (size_t)e * 8);
    float4 z0 = ef4[0], z1 = ef4[1];
    union { int4 i; h2 h[4]; } cv;
    cv.h[0] = h2{(_Float16)z0.x, (_Float16)z0.y};
    cv.h[1] = h2{(_Float16)z0.z, (_Float16)z0.w};
    cv.h[2] = h2{(_Float16)z1.x, (_Float16)z1.y};
    cv.h[3] = h2{(_Float16)z1.z, (_Float16)z1.w};
    int4* dst = (int4*)(emeta + slot);
    dst[0] = make_int4(u, v, e, 0);
    dst[1] = cv.i;
  } else {
    v_sorted[slot] = v;
    e_orig[slot] = e;
  }
}

// --- layer-0 aggregate over fp16 x (32-wide rows): 4 nodes/wave ------------
// tot = dv * (sum_u dinv[u]*x[u] + dv*x[self])
__global__ __launch_bounds__(TPB) void aggregate32h(const __half* __restrict__ X,
                                                    const int* __restrict__ u_sorted,
                                                    const int* __restrict__ row_ptr,
                                                    const float* __restrict__ dinv,
                                                    float* __restrict__ xagg, int n) {
  int wave = (blockIdx.x * TPB + threadIdx.x) >> 6;
  int lane = threadIdx.x & 63;
  int q = lane >> 4, f2 = lane & 15;
  int node = wave * 4 + q;
  bool valid = node < n;
  int rs = 0, re = 0;
  float dv = 0.f;
  if (valid) { rs = row_ptr[node]; re = row_ptr[node + 1]; dv = dinv[node]; }
  const __half2* selfp = (const __half2*)(X + (size_t)(valid ? node : 0) * 32);
  float2 sf = __half22float2(selfp[f2]);
  float2 acc0 = make_float2(sf.x * dv, sf.y * dv);  // dv*x_self
  float2 acc1 = make_float2(0.f, 0.f);
  int sb = q << 4;
  for (int base = rs; base < re; base += 16) {
    int m = re - base;
    if (m > 16) m = 16;
    int uj = 0;
    float wj = 0.f;
    if (f2 < m) { uj = u_sorted[base + f2]; wj = dinv[uj]; }
    int k = 0;
    for (; k + 1 < m; k += 2) {
      int u0 = __shfl(uj, sb + k), u1 = __shfl(uj, sb + k + 1);
      float w0 = __shfl(wj, sb + k), w1 = __shfl(wj, sb + k + 1);
      float2 v0 = __half22float2(((const __half2*)(X + (size_t)u0 * 32))[f2]);
      float2 v1 = __half22float2(((const __half2*)(X + (size_t)u1 * 32))[f2]);
      acc0.x = fmaf(v0.x, w0, acc0.x);
      acc0.y = fmaf(v0.y, w0, acc0.y);
      acc1.x = fmaf(v1.x, w1, acc1.x);
      acc1.y = fmaf(v1.y, w1, acc1.y);
    }
    if (k < m) {
      int u0 = __shfl(uj, sb + k);
      float w0 = __shfl(wj, sb + k);
      float2 v0 = __half22float2(((const __half2*)(X + (size_t)u0 * 32))[f2]);
      acc0.x = fmaf(v0.x, w0, acc0.x);
      acc0.y = fmaf(v0.y, w0, acc0.y);
    }
  }
  if (valid) {
    float2 r = make_float2(dv * (acc0.x + acc1.x), dv * (acc0.y + acc1.y));
    ((float2*)(xagg + (size_t)node * 32))[f2] = r;
  }
}

// --- layer-0 linear with bias+relu: H1 = relu(xagg @ W0 + b0), fp32 out ----
__global__ __launch_bounds__(TPB) void lin32_br(const float* __restrict__ A,
                                                const float* __restrict__ W,
                                                const float* __restrict__ bias,
                                                float* __restrict__ B, int n) {
  __shared__ __align__(16) float Ws[32 * 64];
  __shared__ float bs[64];
  int tid = threadIdx.x;
  for (int i = tid; i < 32 * 64; i += TPB) Ws[i] = W[i];
  if (tid < 64) bs[tid] = bias[tid];
  __syncthreads();
  int node = blockIdx.x * TPB + tid;
  if (node >= n) return;
  const float4* a4 = (const float4*)(A + (size_t)node * 32);
  float acc[64];
#pragma unroll
  for (int j = 0; j < 64; ++j) acc[j] = bs[j];
  for (int i4 = 0; i4 < 8; ++i4) {
    float4 z = a4[i4];
    fma_row64(z.x, &Ws[(4 * i4 + 0) * 64], acc);
    fma_row64(z.y, &Ws[(4 * i4 + 1) * 64], acc);
    fma_row64(z.z, &Ws[(4 * i4 + 2) * 64], acc);
    fma_row64(z.w, &Ws[(4 * i4 + 3) * 64], acc);
  }
  float4* b4 = (float4*)(B + (size_t)node * 64);
#pragma unroll
  for (int j4 = 0; j4 < 16; ++j4)
    b4[j4] = make_float4(fmaxf(acc[4 * j4 + 0], 0.f), fmaxf(acc[4 * j4 + 1], 0.f),
                         fmaxf(acc[4 * j4 + 2], 0.f), fmaxf(acc[4 * j4 + 3], 0.f));
}

// --- node linear (64 -> 64), fp32 in, fp16 out -----------------------------
__global__ __launch_bounds__(TPB) void lin_node64h(const float* __restrict__ A,
                                                   const float* __restrict__ W,
                                                   __half* __restrict__ Bh, int n) {
  __shared__ __align__(16) float Ws[64 * 64];
  int tid = threadIdx.x;
  for (int i = tid; i < 64 * 64; i += TPB) Ws[i] = W[i];
  __syncthreads();
  int node = blockIdx.x * TPB + tid;
  if (node >= n) return;
  const float4* a4 = (const float4*)(A + (size_t)node * 64);
  float acc[64];
#pragma unroll
  for (int j = 0; j < 64; ++j) acc[j] = 0.f;
  for (int i4 = 0; i4 < 16; ++i4) {
    float4 z = a4[i4];
    fma_row64(z.x, &Ws[(4 * i4 + 0) * 64], acc);
    fma_row64(z.y, &Ws[(4 * i4 + 1) * 64], acc);
    fma_row64(z.z, &Ws[(4 * i4 + 2) * 64], acc);
    fma_row64(z.w, &Ws[(4 * i4 + 3) * 64], acc);
  }
  __half2* o2 = (__half2*)(Bh + (size_t)node * 64);
#pragma unroll
  for (int j2 = 0; j2 < 32; ++j2)
    o2[j2] = __floats2half2_rn(acc[2 * j2 + 0], acc[2 * j2 + 1]);
}

// --- aggregation (64-wide, fp16 rows): 2 nodes/wave, half2 lanes -----------
__global__ __launch_bounds__(TPB) void aggregateh(const __half* __restrict__ Bh,
                                                  const int* __restrict__ u_sorted,
                                                  const int* __restrict__ row_ptr,
                                                  const float* __restrict__ dinv,
                                                  const float* __restrict__ bias,
                                                  float* __restrict__ A, int n) {
  int wave = (blockIdx.x * TPB + threadIdx.x) >> 6;
  int lane = threadIdx.x & 63;
  int half = lane >> 5, f2 = lane & 31;
  int node = wave * 2 + half;
  bool valid = node < n;
  int rs = 0, re = 0;
  float dv = 0.f;
  if (valid) { rs = row_ptr[node]; re = row_ptr[node + 1]; dv = dinv[node]; }
  const __half2* selfp = (const __half2*)(Bh + (size_t)(valid ? node : 0) * 64);
  float2 sf = __half22float2(selfp[f2]);
  float2 acc0 = make_float2(sf.x * dv, sf.y * dv);  // dv*h_self
  float2 acc1 = make_float2(0.f, 0.f);
  float2 acc2 = make_float2(0.f, 0.f);
  float2 acc3 = make_float2(0.f, 0.f);
  int sb = half << 5;
  for (int base = rs; base < re; base += 32) {
    int m = re - base;
    if (m > 32) m = 32;
    int uj = 0;
    float wj = 0.f;
    if (f2 < m) { uj = u_sorted[base + f2]; wj = dinv[uj]; }
    int k = 0;
    for (; k + 3 < m; k += 4) {
      int u0 = __shfl(uj, sb + k), u1 = __shfl(uj, sb + k + 1);
      int u2 = __shfl(uj, sb + k + 2), u3 = __shfl(uj, sb + k + 3);
      float w0 = __shfl(wj, sb + k), w1 = __shfl(wj, sb + k + 1);
      float w2 = __shfl(wj, sb + k + 2), w3 = __shfl(wj, sb + k + 3);
      float2 v0 = __half22float2(((const __half2*)(Bh + (size_t)u0 * 64))[f2]);
      float2 v1 = __half22float2(((const __half2*)(Bh + (size_t)u1 * 64))[f2]);
      float2 v2 = __half22float2(((const __half2*)(Bh + (size_t)u2 * 64))[f2]);
      float2 v3 = __half22float2(((const __half2*)(Bh + (size_t)u3 * 64))[f2]);
      acc0.x = fmaf(v0.x, w0, acc0.x); acc0.y = fmaf(v0.y, w0, acc0.y);
      acc1.x = fmaf(v1.x, w1, acc1.x); acc1.y = fmaf(v1.y, w1, acc1.y);
      acc2.x = fmaf(v2.x, w2, acc2.x); acc2.y = fmaf(v2.y, w2, acc2.y);
      acc3.x = fmaf(v3.x, w3, acc3.x); acc3.y = fmaf(v3.y, w3, acc3.y);
    }
    for (; k < m; ++k) {
      int u0 = __shfl(uj, sb + k);
      float w0 = __shfl(wj, sb + k);
      float2 v0 = __half22float2(((const __half2*)(Bh + (size_t)u0 * 64))[f2]);
      acc0.x = fmaf(v0.x, w0, acc0.x);
      acc0.y = fmaf(v0.y, w0, acc0.y);
    }
  }
  if (valid) {
    float2 bi = ((const float2*)bias)[f2];
    float2 r;
    r.x = fmaxf(dv * ((acc0.x + acc1.x) + (acc2.x + acc3.x)) + bi.x, 0.f);
    r.y = fmaxf(dv * ((acc0.y + acc1.y) + (acc2.y + acc3.y)) + bi.y, 0.f);
    ((float2*)(A + (size_t)node * 64))[f2] = r;
  }
}

// --- fused apre/bpre: fp16 outputs -----------------------------------------
__global__ __launch_bounds__(TPB) void lin_ab(const float* __restrict__ A,
                                              const float* __restrict__ W,
                                              __half* __restrict__ apre,
                                              __half* __restrict__ bpre, int n) {
  __shared__ __align__(16) float Ws[128 * 64];  // 32 KB
  int tid = threadIdx.x;
  for (int i = tid; i < 128 * 64; i += TPB) Ws[i] = W[i];
  __syncthreads();
  int node = blockIdx.x * TPB + tid;
  if (node >= n) return;
  const float4* a4 = (const float4*)(A + (size_t)node * 64);
  float acc[64];
#pragma unroll
  for (int j = 0; j < 64; ++j) acc[j] = 0.f;
  for (int i4 = 0; i4 < 16; ++i4) {
    float4 z = a4[i4];
    fma_row64(z.x, &Ws[(4 * i4 + 0) * 64], acc);
    fma_row64(z.y, &Ws[(4 * i4 + 1) * 64], acc);
    fma_row64(z.z, &Ws[(4 * i4 + 2) * 64], acc);
    fma_row64(z.w, &Ws[(4 * i4 + 3) * 64], acc);
  }
  __half2* o2 = (__half2*)(apre + (size_t)node * 64);
#pragma unroll
  for (int j2 = 0; j2 < 32; ++j2)
    o2[j2] = __floats2half2_rn(acc[2 * j2 + 0], acc[2 * j2 + 1]);
#pragma unroll
  for (int j = 0; j < 64; ++j) acc[j] = 0.f;
  for (int i4 = 0; i4 < 16; ++i4) {
    float4 z = a4[i4];  // L1-hot reread
    fma_row64(z.x, &Ws[(64 + 4 * i4 + 0) * 64], acc);
    fma_row64(z.y, &Ws[(64 + 4 * i4 + 1) * 64], acc);
    fma_row64(z.z, &Ws[(64 + 4 * i4 + 2) * 64], acc);
    fma_row64(z.w, &Ws[(64 + 4 * i4 + 3) * 64], acc);
  }
  o2 = (__half2*)(bpre + (size_t)node * 64);
#pragma unroll
  for (int j2 = 0; j2 < 32; ++j2)
    o2[j2] = __floats2half2_rn(acc[2 * j2 + 0], acc[2 * j2 + 1]);
}

// --- edge MLP, CSR order, fdot2 path ---------------------------------------
template <bool META>
__global__ __launch_bounds__(TPB) void edge_mlp(
    const __half* __restrict__ apre, const __half* __restrict__ bpre,
    const EMeta* __restrict__ emeta, const int* __restrict__ u_sorted,
    const int* __restrict__ v_sorted, const int* __restrict__ e_orig,
    const float* __restrict__ EF, const h2* __restrict__ w1p,
    const float* __restrict__ bm1, const h2* __restrict__ w2p,
    const float* __restrict__ bm2, const float* __restrict__ Wm3,
    const float* __restrict__ bm3, float* __restrict__ out, int E) {
  int t = blockIdx.x * TPB + threadIdx.x;
  if (t >= E) return;
  int u, v, e;
  h2 efh[4];
  if constexpr (META) {
    const int4* mp = (const int4*)(emeta + t);
    int4 lo = mp[0];
    int4 hi = mp[1];
    u = lo.x; v = lo.y; e = lo.z;
    union { int4 i; h2 h[4]; } cv;
    cv.i = hi;
    efh[0] = cv.h[0]; efh[1] = cv.h[1]; efh[2] = cv.h[2]; efh[3] = cv.h[3];
  } else {
    u = u_sorted[t]; v = v_sorted[t]; e = e_orig[t];
    const float4* ef4 = (const float4*)(EF + (size_t)e * 8);
    float4 z0 = ef4[0], z1 = ef4[1];
    efh[0] = h2{(_Float16)z0.x, (_Float16)z0.y};
    efh[1] = h2{(_Float16)z0.z, (_Float16)z0.w};
    efh[2] = h2{(_Float16)z1.x, (_Float16)z1.y};
    efh[3] = h2{(_Float16)z1.z, (_Float16)z1.w};
  }
  const h2* a2 = (const h2*)(apre + (size_t)u * 64);
  const h2* b2 = (const h2*)(bpre + (size_t)v * 64);  // wave-shared row
  const h2 selLo = h2{(_Float16)1.f, (_Float16)0.f};
  const h2 selHi = h2{(_Float16)0.f, (_Float16)1.f};

  // layer 1: acc[j] = bm1[j] + apre[u][j] + bpre[v][j] + ef . W1e[:,j]
  float acc[64];
#pragma unroll
  for (int j = 0; j < 64; ++j) {
    h2 sel = (j & 1) ? selHi : selLo;
    float a = fdot2(a2[j >> 1], sel, bm1[j]);
    a = fdot2(b2[j >> 1], sel, a);
    const h2* wp = w1p + j * 4;
    a = fdot2(efh[0], wp[0], a);
    a = fdot2(efh[1], wp[1], a);
    a = fdot2(efh[2], wp[2], a);
    a = fdot2(efh[3], wp[3], a);
    acc[j] = a;
  }

  // relu + pack to half2
  h2 zh[32];
#pragma unroll
  for (int i2 = 0; i2 < 32; ++i2)
    zh[i2] = h2{(_Float16)fmaxf(acc[2 * i2 + 0], 0.f),
                (_Float16)fmaxf(acc[2 * i2 + 1], 0.f)};

  // layer 2 (64->32) + layer 3 (32->1)
  float o = bm3[0];
#pragma unroll
  for (int j = 0; j < 32; ++j) {
    float z = bm2[j];
    const h2* wp = w2p + j * 32;
#pragma unroll
    for (int kk = 0; kk < 32; ++kk) z = fdot2(zh[kk], wp[kk], z);
    o = fmaf(fmaxf(z, 0.f), Wm3[j], o);
  }
  out[e] = o;
}

// ---------------------------------------------------------------------------
extern "C" void kernel_launch(void* const* d_in, const int* in_sizes, int n_in,
                              void* d_out, int out_size, void* d_ws, size_t ws_size,
                              hipStream_t stream) {
  const float* x   = (const float*)d_in[0];
  const int*   ei  = (const int*)d_in[1];
  const float* ef  = (const float*)d_in[2];
  const float* W0  = (const float*)d_in[3];
  const float* b0  = (const float*)d_in[4];
  const float* W1  = (const float*)d_in[5];
  const float* b1  = (const float*)d_in[6];
  const float* W2  = (const float*)d_in[7];
  const float* b2  = (const float*)d_in[8];
  const float* Wm1 = (const float*)d_in[9];
  const float* bm1 = (const float*)d_in[10];
  const float* Wm2 = (const float*)d_in[11];
  const float* bm2 = (const float*)d_in[12];
  const float* Wm3 = (const float*)d_in[13];
  const float* bm3 = (const float*)d_in[14];
  float* out = (float*)d_out;

  const int N = in_sizes[0] / 32;
  const int E = in_sizes[2] / 8;

  // workspace carve (256B aligned)
  char* p = (char*)d_ws;
  auto carve = [&](size_t bytes) {
    void* r = (void*)p;
    p += ((bytes + 255) / 256) * 256;
    return r;
  };
  int*    cnt      = (int*)carve((size_t)N * 4);
  int*    row_ptr  = (int*)carve((size_t)(N + 1) * 4);
  int*    fill     = (int*)carve((size_t)N * 4);
  float*  dinv     = (float*)carve((size_t)N * 4);
  int*    bsums    = (int*)carve(4096);
  int*    flag     = (int*)carve(256);
  h2*     w1p      = (h2*)carve(256 * 4);
  h2*     w2p      = (h2*)carve(1024 * 4);
  int*    u_sorted = (int*)carve((size_t)E * 4);
  float*  hA       = (float*)carve((size_t)N * 64 * 4);  // h1/h3
  float*  hB       = (float*)carve((size_t)N * 64 * 4);  // h2; head = xagg
  __half* linh     = (__half*)carve((size_t)N * 64 * 2); // fp16 lin outputs
  __half* apreh    = (__half*)carve((size_t)N * 64 * 2); // head doubles as xh
  __half* bpreh    = (__half*)carve((size_t)N * 64 * 2);

  // branch: EMeta path if workspace allows, else R7-style gather path
  size_t used = (size_t)(p - (char*)d_ws);
  size_t meta_need = (((size_t)E * 32 + 255) / 256) * 256;
  bool use_meta = (used + meta_need <= ws_size);
  EMeta* emeta = nullptr;
  int *v_sorted = nullptr, *e_orig = nullptr;
  if (use_meta) {
    emeta = (EMeta*)carve((size_t)E * 32);
  } else {
    v_sorted = (int*)carve((size_t)E * 4);
    e_orig   = (int*)carve((size_t)E * 4);
    if ((size_t)(p - (char*)d_ws) > ws_size) return;  // cannot run
  }

  // aliases (lifetime-disjoint):
  float* xagg = hB;    // dead after lin32_br; hB written later
  __half* xh = apreh;  // dead after aggregate32h; apreh written later

  const int EB = (E + TPB - 1) / TPB;
  const int NB = (N + TPB - 1) / TPB;
  const int SB = (N + 1023) / 1024;
  const int AB2 = (((N + 1) / 2) + 3) / 4;  // 2 nodes/wave, 4 waves/block
  const int AB4 = (((N + 3) / 4) + 3) / 4;  // 4 nodes/wave, 4 waves/block

  prep<<<NB, TPB, 0, stream>>>(cnt, fill, N, ei, flag, x, xh);
  count_deg<<<EB, TPB, 0, stream>>>(ei, flag, cnt, E);
  scan1<<<SB, TPB, 0, stream>>>(cnt, row_ptr, bsums, dinv, N);
  scan2w<<<1, TPB, 0, stream>>>(bsums, SB, Wm1 + 128 * 64, Wm2, w1p, w2p);
  scan3<<<NB, TPB, 0, stream>>>(row_ptr, bsums, N, E);
  if (use_meta)
    fill_csr<true><<<EB, TPB, 0, stream>>>(ei, flag, row_ptr, fill, ef, u_sorted,
                                           emeta, v_sorted, e_orig, E);
  else
    fill_csr<false><<<EB, TPB, 0, stream>>>(ei, flag, row_ptr, fill, ef, u_sorted,
                                            emeta, v_sorted, e_orig, E);

  // GCN layer 0: aggregate fp16 x (4 nodes/wave), then lin+bias+relu -> hA
  aggregate32h<<<AB4, TPB, 0, stream>>>(xh, u_sorted, row_ptr, dinv, xagg, N);
  lin32_br<<<NB, TPB, 0, stream>>>(xagg, W0, b0, hA, N);
  // layer 1: lin (fp16 out) then aggregate (2 nodes/wave) -> hB
  lin_node64h<<<NB, TPB, 0, stream>>>(hA, W1, linh, N);
  aggregateh<<<AB2, TPB, 0, stream>>>(linh, u_sorted, row_ptr, dinv, b1, hB, N);
  // layer 2 -> hA
  lin_node64h<<<NB, TPB, 0, stream>>>(hB, W2, linh, N);
  aggregateh<<<AB2, TPB, 0, stream>>>(linh, u_sorted, row_ptr, dinv, b2, hA, N);

  // edge-MLP layer-1 factorization: apre/bpre fp16
  lin_ab<<<NB, TPB, 0, stream>>>(hA, Wm1, apreh, bpreh, N);

  // edge MLP in CSR order (fdot2 path)
  if (use_meta)
    edge_mlp<true><<<EB, TPB, 0, stream>>>(apreh, bpreh, emeta, u_sorted, v_sorted,
                                           e_orig, ef, w1p, bm1, w2p, bm2, Wm3, bm3,
                                           out, E);
  else
    edge_mlp<false><<<EB, TPB, 0, stream>>>(apreh, bpreh, emeta, u_sorted, v_sorted,
                                            e_orig, ef, w1p, bm1, w2p, bm2, Wm3, bm3,
                                            out, E);
}